// Round 9
// baseline (434.448 us; speedup 1.0000x reference)
//
#include <hip/hip_runtime.h>
#include <hip/hip_bf16.h>

#define BD 8
#define CD 128
#define HD 96
#define WD 96
#define HW (HD*WD)          // 9216
#define NPIX (BD*HW)        // 73728
#define NTOT ((size_t)BD*CD*HW) // 9437184
#define WC 144
#define NG 16
#define KWRE_OFF 37617664   // scratch inside d_out (y overwrites it later)

typedef __hip_bfloat16 bf16;
typedef __attribute__((ext_vector_type(8))) short s8v;   // 8 bf16 (A/B frag)
typedef __attribute__((ext_vector_type(4))) float f4v;   // 4 f32 (C/D frag)

__device__ __forceinline__ float b2f(bf16 v){ return __bfloat162float(v); }
__device__ __forceinline__ bf16  f2b(float v){ return __float2bfloat16(v); }
__device__ __forceinline__ short f2bs(float f){ union{ bf16 h; short s; } u; u.h = f2b(f); return u.s; }
__device__ __forceinline__ float bs2f(short s){ union{ bf16 h; short s; } u; u.s = s; return b2f(u.h); }

struct TensPtrs { const void* p[14]; };

__device__ __constant__ int dNelem[14] = {
    9437184, 36864, 16384, 9216, 144, 144, 144, 16384, 128, 128, 8192, 64, 16384, 256
};
__device__ __constant__ int dCanonOff[14] = {
    0, 0, 36864, 53248, 62464, 62608, 62752, 62896, 79280, 79408, 79536, 87728, 87792, 104176
};
__device__ __constant__ int dBOff[14] = {
    -1, 0, 36864, 53248, -1, -1, -1, 62464, -1, -1, -1, -1, -1, -1
};
#define CO_EB2  62464
#define CO_GNG  62608
#define CO_GNB  62752
#define CO_BNG  79280
#define CO_BNB  79408
#define CO_SW1  79536
#define CO_SB1  87728
#define CO_SW2  87792
#define CO_SB2  104176
#define BO_KW   0
#define BO_EW1  36864
#define BO_EW2  53248
#define BO_C1W  62464

// ---------------- detect ----------------
__global__ void k_detect(TensPtrs tp, int* __restrict__ flags){
    int i = blockIdx.x; int tid = threadIdx.x;
    int n = dNelem[i];
    int m = n < 4096 ? n : 4096;
    int pairs = m >> 1;
    const unsigned short* u = (const unsigned short*)tp.p[i];
    int v = 0;
    for (int j = tid; j < pairs; j += 64){
        unsigned short lo = u[2*j], hi = u[2*j+1];
        int e = (lo >> 7) & 0xFF;
        bool wild = (e >= 0xBE) || (e > 0 && e < 0x40);
        if (wild || (lo == 0 && hi != 0)) v++;
    }
    __shared__ int sv[64];
    sv[tid] = v; __syncthreads();
    for (int st = 32; st > 0; st >>= 1){
        if (tid < st) sv[tid] += sv[tid+st];
        __syncthreads();
    }
    if (tid == 0) flags[i] = (sv[0]*8 > pairs) ? 1 : 0;
}

// ---------------- canon ----------------
__global__ void k_canon(TensPtrs tp, const int* __restrict__ flags,
                        float* __restrict__ canonf, short* __restrict__ canonb){
    int i = blockIdx.x + 1;
    int n = dNelem[i]; int off = dCanonOff[i]; int bo = dBOff[i];
    bool f32 = flags[i] != 0;
    for (int j = threadIdx.x; j < n; j += 256){
        float v = f32 ? ((const float*)tp.p[i])[j] : b2f(((const bf16*)tp.p[i])[j]);
        canonf[off + j] = v;
        if (bo >= 0) canonb[bo + j] = f2bs(v);
    }
}

// ---------------- reorder key weights: [g][oc][ic][t] -> [g][t][oc][ic] ----------------
__global__ void k_reorder_kw(const short* __restrict__ canonb, short* __restrict__ kwre){
    int idx = blockIdx.x*256 + threadIdx.x;   // 36864
    if (idx >= 36864) return;
    int g = idx / 9216, rem = idx - g*9216;
    int oc = rem / 288, r2 = rem - oc*288;
    int ic = r2 / 9, t = r2 - ic*9;
    kwre[g*9216 + t*1024 + oc*32 + ic] = canonb[BO_KW + idx];
}

__global__ void k_zero(float* __restrict__ p, int n){
    int i = blockIdx.x*256 + threadIdx.x;
    if (i < n) p[i] = 0.f;
}

// ---------------- keyconv MFMA ----------------
__global__ void k_keyconv_mfma(const void* __restrict__ x, const int* __restrict__ flags,
                               const short* __restrict__ kwre, bf16* __restrict__ kout){
    __shared__ short xt[588*32];     // [pixel(6x98)][ic] 37632 B
    int blk = blockIdx.x;
    int band = blk % 24, g = (blk/24) & 3, b = blk / 96;
    int r0 = band*4;
    int tid = threadIdx.x;
    bool F = flags[0] != 0;
    for (int idx = tid; idx < 2352; idx += 256){
        int oct = idx / 588, pxl = idx - oct*588;
        int pr = pxl / 98, pc = pxl - pr*98;
        int ir = r0 - 1 + pr, icol = pc - 1;
        bool inb = ((unsigned)ir < 96u) & ((unsigned)icol < 96u);
        size_t base = ((size_t)b*CD + g*32 + oct*8)*HW + ir*WD + icol;
        s8v tmp;
        #pragma unroll
        for (int j = 0; j < 8; ++j){
            float v = 0.f;
            if (inb) v = F ? ((const float*)x)[base + (size_t)j*HW]
                           : b2f(((const bf16*)x)[base + (size_t)j*HW]);
            tmp[j] = f2bs(v);
        }
        *(s8v*)(xt + pxl*32 + oct*8) = tmp;
    }
    __syncthreads();
    int wave = tid >> 6, lane = tid & 63, l15 = lane & 15, quad = lane >> 4;
    f4v acc[2][6];
    #pragma unroll
    for (int m = 0; m < 2; ++m)
        #pragma unroll
        for (int n = 0; n < 6; ++n) acc[m][n] = (f4v){0.f,0.f,0.f,0.f};
    const short* kg = kwre + g*9216;
    for (int t = 0; t < 9; ++t){
        s8v A0 = *(const s8v*)(kg + t*1024 + l15*32 + quad*8);
        s8v A1 = *(const s8v*)(kg + t*1024 + (16+l15)*32 + quad*8);
        int pbase = (wave + t/3)*98 + (t%3) + l15;
        #pragma unroll
        for (int n = 0; n < 6; ++n){
            s8v B = *(const s8v*)(xt + (pbase + n*16)*32 + quad*8);
            acc[0][n] = __builtin_amdgcn_mfma_f32_16x16x32_bf16(A0, B, acc[0][n], 0, 0, 0);
            acc[1][n] = __builtin_amdgcn_mfma_f32_16x16x32_bf16(A1, B, acc[1][n], 0, 0, 0);
        }
    }
    int r = r0 + wave;
    #pragma unroll
    for (int m = 0; m < 2; ++m)
        #pragma unroll
        for (int n = 0; n < 6; ++n)
            #pragma unroll
            for (int reg = 0; reg < 4; ++reg){
                int oc = g*32 + m*16 + quad*4 + reg;
                int px = n*16 + l15;
                kout[((size_t)b*CD + oc)*HW + r*WD + px] = f2b(fmaxf(acc[m][n][reg], 0.f));
            }
}

// ---------------- vconv MFMA ----------------
__global__ void k_vconv_mfma(const void* __restrict__ x, const int* __restrict__ flags,
                             const short* __restrict__ c1wb, bf16* __restrict__ vout){
    __shared__ short xt[96*136];
    int blk = blockIdx.x; int b = blk / 96, r = blk % 96;
    int tid = threadIdx.x;
    bool F = flags[0] != 0;
    for (int idx = tid; idx < 1536; idx += 256){
        int oct = idx / 96, px = idx - oct*96;
        size_t base = ((size_t)b*CD + oct*8)*HW + r*WD + px;
        s8v tmp;
        #pragma unroll
        for (int j = 0; j < 8; ++j){
            float v = F ? ((const float*)x)[base + (size_t)j*HW]
                        : b2f(((const bf16*)x)[base + (size_t)j*HW]);
            tmp[j] = f2bs(v);
        }
        *(s8v*)(xt + px*136 + oct*8) = tmp;
    }
    __syncthreads();
    int wave = tid >> 6, lane = tid & 63, l15 = lane & 15, quad = lane >> 4;
    f4v acc[2][6];
    #pragma unroll
    for (int m = 0; m < 2; ++m)
        #pragma unroll
        for (int n = 0; n < 6; ++n) acc[m][n] = (f4v){0.f,0.f,0.f,0.f};
    for (int k0 = 0; k0 < 128; k0 += 32){
        s8v Bf[6];
        #pragma unroll
        for (int n = 0; n < 6; ++n) Bf[n] = *(const s8v*)(xt + (n*16+l15)*136 + k0 + quad*8);
        #pragma unroll
        for (int m = 0; m < 2; ++m){
            int oc0 = (wave*2 + m)*16;
            s8v A = *(const s8v*)(c1wb + BO_C1W + (oc0 + l15)*128 + k0 + quad*8);
            #pragma unroll
            for (int n = 0; n < 6; ++n)
                acc[m][n] = __builtin_amdgcn_mfma_f32_16x16x32_bf16(A, Bf[n], acc[m][n], 0, 0, 0);
        }
    }
    #pragma unroll
    for (int m = 0; m < 2; ++m)
        #pragma unroll
        for (int n = 0; n < 6; ++n)
            #pragma unroll
            for (int reg = 0; reg < 4; ++reg){
                int oc = (wave*2+m)*16 + quad*4 + reg;
                int px = n*16 + l15;
                vout[((size_t)b*CD + oc)*HW + r*WD + px] = f2b(acc[m][n][reg]);
            }
}

// ================= FAST PATH =================
__global__ void k_embed_stats(const void* __restrict__ x, const int* __restrict__ flags,
                              const bf16* __restrict__ kbuf, const short* __restrict__ canonb,
                              const float* __restrict__ canonf,
                              unsigned short* __restrict__ w1b,
                              float* __restrict__ gsum_s, float* __restrict__ gsq_s){
    __shared__ short qk[48*136];     // 13056 B, one 128-ch half at a time
    __shared__ short w1s[48*72];     // 6912 B
    __shared__ float gacc[16], gacc2[16];
    const short* ew1b = canonb + BO_EW1;
    const short* ew2b = canonb + BO_EW2;
    const float* eb2f = canonf + CO_EB2;
    int blk = blockIdx.x;
    int px0 = (blk & 1)*48, r = (blk >> 1) % 96, b = blk / 192;
    int tid = threadIdx.x;
    bool F = flags[0] != 0;
    int wave = tid >> 6, lane = tid & 63, l15 = lane & 15, quad = lane >> 4;
    if (tid < 16){ gacc[tid] = 0.f; gacc2[tid] = 0.f; }
    for (int idx = tid; idx < 768; idx += 256){
        int oct = idx / 48, px = idx - oct*48;
        size_t base = ((size_t)b*CD + oct*8)*HW + r*WD + px0 + px;
        s8v tmp;
        #pragma unroll
        for (int j = 0; j < 8; ++j){
            float v = F ? ((const float*)x)[base + (size_t)j*HW]
                        : b2f(((const bf16*)x)[base + (size_t)j*HW]);
            tmp[j] = f2bs(v);
        }
        *(s8v*)(qk + px*136 + oct*8) = tmp;
    }
    __syncthreads();
    f4v a1[3];
    #pragma unroll
    for (int n = 0; n < 3; ++n) a1[n] = (f4v){0.f,0.f,0.f,0.f};
    int mb = wave*16;
    for (int k0 = 0; k0 < 128; k0 += 32){
        s8v A = *(const s8v*)(ew1b + (mb + l15)*256 + k0 + quad*8);
        #pragma unroll
        for (int n = 0; n < 3; ++n){
            s8v Bf = *(const s8v*)(qk + (n*16+l15)*136 + k0 + quad*8);
            a1[n] = __builtin_amdgcn_mfma_f32_16x16x32_bf16(A, Bf, a1[n], 0, 0, 0);
        }
    }
    __syncthreads();
    {
        const short* kb = (const short*)kbuf;
        for (int idx = tid; idx < 768; idx += 256){
            int oct = idx / 48, px = idx - oct*48;
            size_t base = ((size_t)b*CD + oct*8)*HW + r*WD + px0 + px;
            s8v tmp;
            #pragma unroll
            for (int j = 0; j < 8; ++j) tmp[j] = kb[base + (size_t)j*HW];
            *(s8v*)(qk + px*136 + oct*8) = tmp;
        }
    }
    __syncthreads();
    for (int k0 = 128; k0 < 256; k0 += 32){
        s8v A = *(const s8v*)(ew1b + (mb + l15)*256 + k0 + quad*8);
        #pragma unroll
        for (int n = 0; n < 3; ++n){
            s8v Bf = *(const s8v*)(qk + (n*16+l15)*136 + (k0-128) + quad*8);
            a1[n] = __builtin_amdgcn_mfma_f32_16x16x32_bf16(A, Bf, a1[n], 0, 0, 0);
        }
    }
    #pragma unroll
    for (int n = 0; n < 3; ++n)
        #pragma unroll
        for (int reg = 0; reg < 4; ++reg){
            int ch = mb + quad*4 + reg;
            int px = n*16 + l15;
            w1s[px*72 + ch] = f2bs(fmaxf(a1[n][reg], 0.f));
        }
    __syncthreads();
    size_t gpx0 = (size_t)b*HW + r*WD + px0;
    for (int idx = tid; idx < 768; idx += 256){
        int px = idx >> 4, s4 = idx & 15;
        ushort4 v4 = *(const ushort4*)((const unsigned short*)w1s + px*72 + s4*4);
        *(ushort4*)(w1b + (gpx0 + px)*64 + s4*4) = v4;
    }
    {
        f4v a2[3][3];
        #pragma unroll
        for (int i = 0; i < 3; ++i)
            #pragma unroll
            for (int n = 0; n < 3; ++n) a2[i][n] = (f4v){0.f,0.f,0.f,0.f};
        for (int k0 = 0; k0 < 64; k0 += 32){
            s8v Bf[3];
            #pragma unroll
            for (int n = 0; n < 3; ++n) Bf[n] = *(const s8v*)(w1s + (n*16+l15)*72 + k0 + quad*8);
            #pragma unroll
            for (int i = 0; i < 3; ++i){
                int mt = wave + i*4;
                if (mt >= 9) break;
                s8v A = *(const s8v*)(ew2b + (mt*16 + l15)*64 + k0 + quad*8);
                #pragma unroll
                for (int n = 0; n < 3; ++n)
                    a2[i][n] = __builtin_amdgcn_mfma_f32_16x16x32_bf16(A, Bf[n], a2[i][n], 0, 0, 0);
            }
        }
        #pragma unroll
        for (int i = 0; i < 3; ++i){
            int mt = wave + i*4;
            if (mt >= 9) break;
            #pragma unroll
            for (int n = 0; n < 3; ++n)
                #pragma unroll
                for (int reg = 0; reg < 4; ++reg){
                    int o = mt*16 + quad*4 + reg;
                    float v = a2[i][n][reg] + eb2f[o];
                    float s = v, q = v*v;
                    #pragma unroll
                    for (int off = 1; off < 16; off <<= 1){
                        s += __shfl_xor(s, off);
                        q += __shfl_xor(q, off);
                    }
                    if (l15 == 0){
                        int g = o / 9;
                        atomicAdd(&gacc[g], s);
                        atomicAdd(&gacc2[g], q);
                    }
                }
        }
    }
    __syncthreads();
    if (tid < 16){
        int slot = blk & 63;
        atomicAdd(&gsum_s[(b*NG + tid)*64 + slot], gacc[tid]);
        atomicAdd(&gsq_s [(b*NG + tid)*64 + slot], gacc2[tid]);
    }
}

// ---------------- embed APPLY v2: LDS-staged local conv ----------------
__global__ void k_embed_apply(const unsigned short* __restrict__ w1b,
                              const short* __restrict__ canonb, const float* __restrict__ canonf,
                              const float* __restrict__ gmean, const float* __restrict__ gistd,
                              const bf16* __restrict__ vbuf, float* __restrict__ yout){
    __shared__ short w1s[48*72];     // 6912 B
    __shared__ short w2s[48*146];    // 14016 B, GN-applied
    __shared__ short vt[32*156];     // 32ch x (3 rows x pitch 52) = 9984 B
    __shared__ float wsc[WC], wbi[WC];
    const short* ew2b = canonb + BO_EW2;
    const float* eb2f = canonf + CO_EB2;
    int blk = blockIdx.x;
    int px0 = (blk & 1)*48, r = (blk >> 1) % 96, b = blk / 192;
    int tid = threadIdx.x;
    int wave = tid >> 6, lane = tid & 63, l15 = lane & 15, quad = lane >> 4;
    if (tid < WC){
        int g = tid/9;
        float m = gmean[b*NG+g], is = gistd[b*NG+g];
        float ga = canonf[CO_GNG + tid], be = canonf[CO_GNB + tid];
        wsc[tid] = is*ga; wbi[tid] = be - m*is*ga;
    }
    size_t gpx0 = (size_t)b*HW + r*WD + px0;
    for (int idx = tid; idx < 768; idx += 256){
        int px = idx >> 4, s4 = idx & 15;
        ushort4 v4 = *(const ushort4*)(w1b + (gpx0 + px)*64 + s4*4);
        *(ushort4*)((unsigned short*)w1s + px*72 + s4*4) = v4;
    }
    __syncthreads();
    // GEMM2 -> w2s (GN applied)
    {
        f4v a2[3][3];
        #pragma unroll
        for (int i = 0; i < 3; ++i)
            #pragma unroll
            for (int n = 0; n < 3; ++n) a2[i][n] = (f4v){0.f,0.f,0.f,0.f};
        for (int k0 = 0; k0 < 64; k0 += 32){
            s8v Bf[3];
            #pragma unroll
            for (int n = 0; n < 3; ++n) Bf[n] = *(const s8v*)(w1s + (n*16+l15)*72 + k0 + quad*8);
            #pragma unroll
            for (int i = 0; i < 3; ++i){
                int mt = wave + i*4;
                if (mt >= 9) break;
                s8v A = *(const s8v*)(ew2b + (mt*16 + l15)*64 + k0 + quad*8);
                #pragma unroll
                for (int n = 0; n < 3; ++n)
                    a2[i][n] = __builtin_amdgcn_mfma_f32_16x16x32_bf16(A, Bf[n], a2[i][n], 0, 0, 0);
            }
        }
        #pragma unroll
        for (int i = 0; i < 3; ++i){
            int mt = wave + i*4;
            if (mt >= 9) break;
            #pragma unroll
            for (int n = 0; n < 3; ++n)
                #pragma unroll
                for (int reg = 0; reg < 4; ++reg){
                    int o = mt*16 + quad*4 + reg;
                    int px = n*16 + l15;
                    float val = a2[i][n][reg] + eb2f[o];
                    w2s[px*146 + o] = f2bs(val*wsc[o] + wbi[o]);
                }
        }
    }
    __syncthreads();
    // local conv in 4 chunks of 32 channels, v halo staged in LDS
    const short* vb16 = (const short*)vbuf;
    for (int cq = 0; cq < 4; ++cq){
        for (int idx = tid; idx < 4800; idx += 256){
            int ch = idx / 150, rem = idx - ch*150;
            int rr = rem / 50, cc = rem - rr*50;
            int row = r - 1 + rr, col = px0 - 1 + cc;
            short v = 0;
            if ((unsigned)row < 96u && (unsigned)col < 96u)
                v = vb16[((size_t)b*CD + cq*32 + ch)*HW + row*WD + col];
            vt[ch*156 + rr*52 + cc] = v;
        }
        __syncthreads();
        for (int it = tid; it < 1536; it += 256){
            int cl = it / 48, px = it - cl*48;
            int c = cq*32 + cl;
            int g9 = (c >> 3)*9;
            const short* vrow = vt + cl*156 + px;
            const short* wrow = w2s + px*146 + g9;
            float acc = 0.f;
            #pragma unroll
            for (int t = 0; t < 9; ++t)
                acc += bs2f(vrow[(t/3)*52 + (t%3)]) * bs2f(wrow[t]);
            yout[((size_t)b*CD + c)*HW + r*WD + px0 + px] = acc;
        }
        __syncthreads();
    }
}

__global__ void k_bnstat(const float* __restrict__ y, float* __restrict__ bnsum_s,
                         float* __restrict__ bnss_s){
    int blk = blockIdx.x;
    int c = blk >> 4, slice = blk & 15;
    int tid = threadIdx.x;
    float s = 0.f, ss = 0.f;
    int j0 = slice*4608;
    for (int k = 0; k < 18; ++k){
        int j = j0 + k*256 + tid;
        int b = j / HW, p = j - b*HW;
        float v = y[((size_t)b*CD + c)*HW + p];
        s += v; ss += v*v;
    }
    __shared__ float sh[256], sh2[256];
    sh[tid] = s; sh2[tid] = ss;
    __syncthreads();
    for (int st = 128; st > 0; st >>= 1){
        if (tid < st){ sh[tid] += sh[tid+st]; sh2[tid] += sh2[tid+st]; }
        __syncthreads();
    }
    if (tid == 0){
        bnsum_s[c*256 + slice] = sh[0];
        bnss_s [c*256 + slice] = sh2[0];
    }
}

// ================= FALLBACK (R6 embed) =================
template<bool APPLY>
__global__ void k_embed_mfma(const void* __restrict__ x, const int* __restrict__ flags,
                             const bf16* __restrict__ kbuf, const short* __restrict__ canonb,
                             const float* __restrict__ canonf,
                             const float* __restrict__ gmean, const float* __restrict__ gistd,
                             const bf16* __restrict__ vbuf, float* __restrict__ yout,
                             float* __restrict__ gsum_s, float* __restrict__ gsq_s,
                             float* __restrict__ bnsum_s, float* __restrict__ bnss_s){
    __shared__ char buf0[26624];
    __shared__ short w1s[48*72];
    __shared__ short w2s[48*152];
    __shared__ float wsc[WC], wbi[WC];
    __shared__ float blks[256], blkq[256];
    short* qk = (short*)buf0;
    float* yt = (float*)buf0;
    const short* ew1b = canonb + BO_EW1;
    const short* ew2b = canonb + BO_EW2;
    const float* eb2f = canonf + CO_EB2;
    int blk = blockIdx.x;
    int px0 = (blk & 1)*48, r = (blk >> 1) % 96, b = blk / 192;
    int tid = threadIdx.x;
    bool F = flags[0] != 0;
    if (APPLY && tid < WC){
        int g = tid/9;
        float m = gmean[b*NG+g], is = gistd[b*NG+g];
        float ga = canonf[CO_GNG + tid], be = canonf[CO_GNB + tid];
        wsc[tid] = is*ga; wbi[tid] = be - m*is*ga;
    }
    for (int idx = tid; idx < 128*48; idx += 256){
        int c = idx / 48, px = idx - c*48;
        size_t off = ((size_t)b*CD + c)*HW + r*WD + px0 + px;
        float v = F ? ((const float*)x)[off] : b2f(((const bf16*)x)[off]);
        qk[px*264 + c] = f2bs(v);
    }
    for (int idx = tid; idx < 128*48; idx += 256){
        int c = idx / 48, px = idx - c*48;
        qk[px*264 + 128 + c] = ((const short*)kbuf)[((size_t)b*CD + c)*HW + r*WD + px0 + px];
    }
    __syncthreads();
    int wave = tid >> 6, lane = tid & 63, l15 = lane & 15, quad = lane >> 4;
    {
        f4v a1[3];
        #pragma unroll
        for (int n = 0; n < 3; ++n) a1[n] = (f4v){0.f,0.f,0.f,0.f};
        int mb = wave*16;
        for (int k0 = 0; k0 < 256; k0 += 32){
            s8v A = *(const s8v*)(ew1b + (mb + l15)*256 + k0 + quad*8);
            #pragma unroll
            for (int n = 0; n < 3; ++n){
                s8v Bf = *(const s8v*)(qk + (n*16+l15)*264 + k0 + quad*8);
                a1[n] = __builtin_amdgcn_mfma_f32_16x16x32_bf16(A, Bf, a1[n], 0, 0, 0);
            }
        }
        __syncthreads();
        #pragma unroll
        for (int n = 0; n < 3; ++n)
            #pragma unroll
            for (int reg = 0; reg < 4; ++reg){
                int ch = mb + quad*4 + reg;
                int px = n*16 + l15;
                w1s[px*72 + ch] = f2bs(fmaxf(a1[n][reg], 0.f));
            }
    }
    __syncthreads();
    {
        f4v a2[3][3];
        #pragma unroll
        for (int i = 0; i < 3; ++i)
            #pragma unroll
            for (int n = 0; n < 3; ++n) a2[i][n] = (f4v){0.f,0.f,0.f,0.f};
        for (int k0 = 0; k0 < 64; k0 += 32){
            s8v Bf[3];
            #pragma unroll
            for (int n = 0; n < 3; ++n) Bf[n] = *(const s8v*)(w1s + (n*16+l15)*72 + k0 + quad*8);
            #pragma unroll
            for (int i = 0; i < 3; ++i){
                int mt = wave + i*4;
                if (mt >= 9) break;
                s8v A = *(const s8v*)(ew2b + (mt*16 + l15)*64 + k0 + quad*8);
                #pragma unroll
                for (int n = 0; n < 3; ++n)
                    a2[i][n] = __builtin_amdgcn_mfma_f32_16x16x32_bf16(A, Bf[n], a2[i][n], 0, 0, 0);
            }
        }
        #pragma unroll
        for (int i = 0; i < 3; ++i){
            int mt = wave + i*4;
            if (mt >= 9) break;
            #pragma unroll
            for (int n = 0; n < 3; ++n)
                #pragma unroll
                for (int reg = 0; reg < 4; ++reg){
                    int o = mt*16 + quad*4 + reg;
                    int px = n*16 + l15;
                    float val = a2[i][n][reg] + eb2f[o];
                    if (APPLY) val = val*wsc[o] + wbi[o];
                    w2s[px*152 + o] = f2bs(val);
                }
        }
    }
    __syncthreads();
    if (!APPLY){
        if (tid < WC){
            int o = tid; float s = 0.f, ss = 0.f;
            for (int px = 0; px < 48; ++px){ float v = bs2f(w2s[px*152+o]); s += v; ss += v*v; }
            int g = o/9; int slot = blk & 63;
            atomicAdd(&gsum_s[(b*NG+g)*64 + slot], s);
            atomicAdd(&gsq_s [(b*NG+g)*64 + slot], ss);
        }
        return;
    }
    if (tid < 192){
        int px = tid % 48, cq = tid / 48;
        int gcol = px0 + px;
        for (int c = cq*32; c < cq*32 + 32; ++c){
            int g9 = (c >> 3)*9;
            const bf16* vb = vbuf + ((size_t)b*CD + c)*HW;
            float acc = 0.f;
            #pragma unroll
            for (int t = 0; t < 9; ++t){
                int ir = r + t/3 - 1, icc = gcol + t%3 - 1;
                if ((unsigned)ir < 96u && (unsigned)icc < 96u)
                    acc += b2f(vb[ir*WD + icc]) * bs2f(w2s[px*152 + g9 + t]);
            }
            yt[c*52 + px] = acc;
        }
    }
    __syncthreads();
    {
        int c = tid & 127, half = tid >> 7;
        float s = 0.f, ss = 0.f;
        for (int px = half*24; px < half*24 + 24; ++px){
            float v = yt[c*52 + px]; s += v; ss += v*v;
        }
        blks[tid] = s; blkq[tid] = ss;
    }
    __syncthreads();
    if (tid < 128){
        float s = blks[tid] + blks[tid+128];
        float ss = blkq[tid] + blkq[tid+128];
        int slot = blk & 255;
        atomicAdd(&bnsum_s[tid*256 + slot], s);
        atomicAdd(&bnss_s [tid*256 + slot], ss);
    }
    for (int idx = tid; idx < 128*48; idx += 256){
        int c = idx / 48, px = idx - c*48;
        yout[((size_t)b*CD + c)*HW + r*WD + px0 + px] = yt[c*52 + px];
    }
}

// ---------------- GN finalize ----------------
__global__ void k_gnfin(const float* __restrict__ gsum_s, const float* __restrict__ gsq_s,
                        float* __restrict__ gmean, float* __restrict__ gistd){
    int i = threadIdx.x;
    float s = 0.f, ss = 0.f;
    for (int k = 0; k < 64; ++k){ s += gsum_s[i*64 + k]; ss += gsq_s[i*64 + k]; }
    float inv = 1.f / (9.f*HW);
    float m = s*inv;
    float var = ss*inv - m*m;
    gmean[i] = m;
    gistd[i] = rsqrtf(var + 1e-5f);
}

// ---------------- BN finalize ----------------
__global__ void k_bnfin(const float* __restrict__ bnsum_s, const float* __restrict__ bnss_s,
                        const float* __restrict__ canonf,
                        float* __restrict__ scale, float* __restrict__ shift){
    int c = threadIdx.x;
    float s = 0.f, ss = 0.f;
    for (int k = 0; k < 256; ++k){ s += bnsum_s[c*256 + k]; ss += bnss_s[c*256 + k]; }
    float inv = 1.f / (float)(BD*HW);
    float m = s*inv;
    float var = ss*inv - m*m;
    float sc = canonf[CO_BNG + c] * rsqrtf(var + 1e-5f);
    scale[c] = sc;
    shift[c] = canonf[CO_BNB + c] - m*sc;
}

// ---------------- BN apply + swish + GAP ----------------
__global__ void k_swishgap(float* __restrict__ ybuf, const bf16* __restrict__ kbuf,
                           const float* __restrict__ scale, const float* __restrict__ shift,
                           float* __restrict__ gap){
    int blk = blockIdx.x;
    int q = blk & 3; int bc = blk >> 2;
    int b = bc / CD, c = bc % CD;
    int tid = threadIdx.x;
    float sc = scale[c], sh = shift[c];
    size_t base = ((size_t)b*CD + c)*HW;
    float gs = 0.f;
    int pend = (q+1)*2304;
    for (int p = q*2304 + tid; p < pend; p += 256){
        float yn = ybuf[base+p] * sc + sh;
        float ys = yn / (1.f + __expf(-yn));
        ybuf[base+p] = ys;
        gs += ys + b2f(kbuf[base+p]);
    }
    __shared__ float shm[256];
    shm[tid] = gs; __syncthreads();
    for (int st = 128; st > 0; st >>= 1){
        if (tid < st) shm[tid] += shm[tid+st];
        __syncthreads();
    }
    if (tid == 0) atomicAdd(&gap[b*CD+c], shm[0]);
}

// ---------------- SE ----------------
__global__ void k_se(const float* __restrict__ gap, const float* __restrict__ canonf,
                     float* __restrict__ p0, float* __restrict__ p1){
    int b = blockIdx.x;
    int tid = threadIdx.x;
    __shared__ float loc[128], h1[64];
    float invhw = 1.f / (float)HW;
    loc[tid]      = gap[b*CD + tid]      * invhw;
    loc[tid + 64] = gap[b*CD + tid + 64] * invhw;
    __syncthreads();
    {
        const float* wr = canonf + CO_SW1 + (size_t)tid*128;
        float acc = canonf[CO_SB1 + tid];
        for (int c = 0; c < 128; ++c) acc += wr[c] * loc[c];
        h1[tid] = fmaxf(acc, 0.f);
    }
    __syncthreads();
    for (int c = tid; c < 128; c += 64){
        float a0 = canonf[CO_SB2 + 2*c], a1 = canonf[CO_SB2 + 2*c+1];
        const float* w0 = canonf + CO_SW2 + (size_t)(2*c)*64;
        const float* w1p = canonf + CO_SW2 + (size_t)(2*c+1)*64;
        for (int j = 0; j < 64; ++j){
            a0 += w0[j] * h1[j];
            a1 += w1p[j] * h1[j];
        }
        float mx = fmaxf(a0, a1);
        float e0 = __expf(a0-mx), e1 = __expf(a1-mx);
        float inv = 1.f / (e0 + e1);
        p0[b*CD+c] = e0*inv;
        p1[b*CD+c] = e1*inv;
    }
}

// ---------------- out ----------------
__global__ void k_out(float* __restrict__ ybuf, const bf16* __restrict__ kbuf,
                      const float* __restrict__ p0, const float* __restrict__ p1){
    size_t idx = (size_t)blockIdx.x*256 + threadIdx.x;
    if (idx >= NTOT) return;
    int bc = (int)(idx / HW);
    int c = bc % CD, b = bc / CD;
    float r = ybuf[idx]*p0[b*CD+c] + b2f(kbuf[idx])*p1[b*CD+c];
    ybuf[idx] = r;
}

extern "C" void kernel_launch(void* const* d_in, const int* in_sizes, int n_in,
                              void* d_out, int out_size, void* d_ws, size_t ws_size,
                              hipStream_t stream) {
    TensPtrs tp;
    for (int i = 0; i < 14; ++i) tp.p[i] = d_in[i];

    float* f = (float*)d_ws;
    float* bnsum_s = f;            // 32768 (zeroed)
    float* bnss_s  = f + 32768;    // 32768 (zeroed)
    float* gsum_s  = f + 65536;    // 8192  (zeroed)
    float* gsq_s   = f + 73728;    // 8192  (zeroed)
    float* gap     = f + 81920;    // 1024  (zeroed)
    float* gmean   = f + 82944;
    float* gistd   = f + 83072;
    float* bscale  = f + 83200;
    float* bshift  = f + 83328;
    float* p0      = f + 83456;
    float* p1      = f + 84480;
    int*   flags = (int*)((char*)d_ws + 393216);
    float* canonf = (float*)((char*)d_ws + 425984);
    short* canonb = (short*)((char*)d_ws + 860160);
    bf16*  kbuf  = (bf16*)((char*)d_ws + 1048576);        // 18.87 MB
    bf16*  vbuf  = kbuf + NTOT;                           // 18.87 MB (ends 38,797,312)
    unsigned short* w1b = (unsigned short*)((char*)d_ws + 38797312);  // 9.44 MB (ends 48,234,496)
    float* ybuf  = (float*)d_out;
    short* kwre = (short*)((char*)d_out + KWRE_OFF);      // scratch in d_out, overwritten by y

    bool fast = ws_size >= 48234496ull;

    k_detect<<<14, 64, 0, stream>>>(tp, flags);
    k_canon<<<13, 256, 0, stream>>>(tp, flags, canonf, canonb);
    k_reorder_kw<<<144, 256, 0, stream>>>(canonb, kwre);
    k_zero<<<324, 256, 0, stream>>>(f, 82944);
    k_keyconv_mfma<<<768, 256, 0, stream>>>(d_in[0], flags, kwre, kbuf);
    if (fast){
        k_embed_stats<<<1536, 256, 0, stream>>>(d_in[0], flags, kbuf, canonb, canonf,
                                                w1b, gsum_s, gsq_s);
        k_gnfin<<<1, 128, 0, stream>>>(gsum_s, gsq_s, gmean, gistd);
        k_vconv_mfma<<<768, 256, 0, stream>>>(d_in[0], flags, canonb, vbuf);
        k_embed_apply<<<1536, 256, 0, stream>>>(w1b, canonb, canonf, gmean, gistd,
                                                vbuf, ybuf);
        k_bnstat<<<2048, 256, 0, stream>>>(ybuf, bnsum_s, bnss_s);
    } else {
        k_embed_mfma<false><<<1536, 256, 0, stream>>>(d_in[0], flags, kbuf, canonb, canonf,
                                                      gmean, gistd, vbuf, ybuf,
                                                      gsum_s, gsq_s, bnsum_s, bnss_s);
        k_gnfin<<<1, 128, 0, stream>>>(gsum_s, gsq_s, gmean, gistd);
        k_vconv_mfma<<<768, 256, 0, stream>>>(d_in[0], flags, canonb, vbuf);
        k_embed_mfma<true><<<1536, 256, 0, stream>>>(d_in[0], flags, kbuf, canonb, canonf,
                                                     gmean, gistd, vbuf, ybuf,
                                                     gsum_s, gsq_s, bnsum_s, bnss_s);
    }
    k_bnfin<<<1, 128, 0, stream>>>(bnsum_s, bnss_s, canonf, bscale, bshift);
    k_swishgap<<<BD*CD*4, 256, 0, stream>>>(ybuf, kbuf, bscale, bshift, gap);
    k_se<<<BD, 64, 0, stream>>>(gap, canonf, p0, p1);
    k_out<<<(int)((NTOT + 255)/256), 256, 0, stream>>>(ybuf, kbuf, p0, p1);
}

// Round 10
// 387.471 us; speedup vs baseline: 1.1212x; 1.1212x over previous
//
#include <hip/hip_runtime.h>
#include <hip/hip_bf16.h>

#define BD 8
#define CD 128
#define HD 96
#define WD 96
#define HW (HD*WD)          // 9216
#define NPIX (BD*HW)        // 73728
#define NTOT ((size_t)BD*CD*HW) // 9437184
#define WC 144
#define NG 16
#define KWRE_OFF 37617664   // scratch inside d_out (y overwrites it later)

typedef __hip_bfloat16 bf16;
typedef __attribute__((ext_vector_type(8))) short s8v;   // 8 bf16 (A/B frag)
typedef __attribute__((ext_vector_type(4))) float f4v;   // 4 f32 (C/D frag)

__device__ __forceinline__ float b2f(bf16 v){ return __bfloat162float(v); }
__device__ __forceinline__ bf16  f2b(float v){ return __float2bfloat16(v); }
__device__ __forceinline__ short f2bs(float f){ union{ bf16 h; short s; } u; u.h = f2b(f); return u.s; }
__device__ __forceinline__ float bs2f(short s){ union{ bf16 h; short s; } u; u.s = s; return b2f(u.h); }

struct TensPtrs { const void* p[14]; };

__device__ __constant__ int dNelem[14] = {
    9437184, 36864, 16384, 9216, 144, 144, 144, 16384, 128, 128, 8192, 64, 16384, 256
};
__device__ __constant__ int dCanonOff[14] = {
    0, 0, 36864, 53248, 62464, 62608, 62752, 62896, 79280, 79408, 79536, 87728, 87792, 104176
};
__device__ __constant__ int dBOff[14] = {
    -1, 0, 36864, 53248, -1, -1, -1, 62464, -1, -1, -1, -1, -1, -1
};
#define CO_EB2  62464
#define CO_GNG  62608
#define CO_GNB  62752
#define CO_BNG  79280
#define CO_BNB  79408
#define CO_SW1  79536
#define CO_SB1  87728
#define CO_SW2  87792
#define CO_SB2  104176
#define BO_KW   0
#define BO_EW1  36864
#define BO_EW2  53248
#define BO_C1W  62464

// ---------------- detect ----------------
__global__ void k_detect(TensPtrs tp, int* __restrict__ flags){
    int i = blockIdx.x; int tid = threadIdx.x;
    int n = dNelem[i];
    int m = n < 4096 ? n : 4096;
    int pairs = m >> 1;
    const unsigned short* u = (const unsigned short*)tp.p[i];
    int v = 0;
    for (int j = tid; j < pairs; j += 64){
        unsigned short lo = u[2*j], hi = u[2*j+1];
        int e = (lo >> 7) & 0xFF;
        bool wild = (e >= 0xBE) || (e > 0 && e < 0x40);
        if (wild || (lo == 0 && hi != 0)) v++;
    }
    __shared__ int sv[64];
    sv[tid] = v; __syncthreads();
    for (int st = 32; st > 0; st >>= 1){
        if (tid < st) sv[tid] += sv[tid+st];
        __syncthreads();
    }
    if (tid == 0) flags[i] = (sv[0]*8 > pairs) ? 1 : 0;
}

// ---------------- canon ----------------
__global__ void k_canon(TensPtrs tp, const int* __restrict__ flags,
                        float* __restrict__ canonf, short* __restrict__ canonb){
    int i = blockIdx.x + 1;
    int n = dNelem[i]; int off = dCanonOff[i]; int bo = dBOff[i];
    bool f32 = flags[i] != 0;
    for (int j = threadIdx.x; j < n; j += 256){
        float v = f32 ? ((const float*)tp.p[i])[j] : b2f(((const bf16*)tp.p[i])[j]);
        canonf[off + j] = v;
        if (bo >= 0) canonb[bo + j] = f2bs(v);
    }
}

// ---------------- reorder key weights: [g][oc][ic][t] -> [g][t][oc][ic] ----------------
__global__ void k_reorder_kw(const short* __restrict__ canonb, short* __restrict__ kwre){
    int idx = blockIdx.x*256 + threadIdx.x;   // 36864
    if (idx >= 36864) return;
    int g = idx / 9216, rem = idx - g*9216;
    int oc = rem / 288, r2 = rem - oc*288;
    int ic = r2 / 9, t = r2 - ic*9;
    kwre[g*9216 + t*1024 + oc*32 + ic] = canonb[BO_KW + idx];
}

__global__ void k_zero(float* __restrict__ p, int n){
    int i = blockIdx.x*256 + threadIdx.x;
    if (i < n) p[i] = 0.f;
}

// ---------------- keyconv MFMA ----------------
__global__ void k_keyconv_mfma(const void* __restrict__ x, const int* __restrict__ flags,
                               const short* __restrict__ kwre, bf16* __restrict__ kout){
    __shared__ short xt[588*32];     // [pixel(6x98)][ic] 37632 B
    int blk = blockIdx.x;
    int band = blk % 24, g = (blk/24) & 3, b = blk / 96;
    int r0 = band*4;
    int tid = threadIdx.x;
    bool F = flags[0] != 0;
    for (int idx = tid; idx < 2352; idx += 256){
        int oct = idx / 588, pxl = idx - oct*588;
        int pr = pxl / 98, pc = pxl - pr*98;
        int ir = r0 - 1 + pr, icol = pc - 1;
        bool inb = ((unsigned)ir < 96u) & ((unsigned)icol < 96u);
        size_t base = ((size_t)b*CD + g*32 + oct*8)*HW + ir*WD + icol;
        s8v tmp;
        #pragma unroll
        for (int j = 0; j < 8; ++j){
            float v = 0.f;
            if (inb) v = F ? ((const float*)x)[base + (size_t)j*HW]
                           : b2f(((const bf16*)x)[base + (size_t)j*HW]);
            tmp[j] = f2bs(v);
        }
        *(s8v*)(xt + pxl*32 + oct*8) = tmp;
    }
    __syncthreads();
    int wave = tid >> 6, lane = tid & 63, l15 = lane & 15, quad = lane >> 4;
    f4v acc[2][6];
    #pragma unroll
    for (int m = 0; m < 2; ++m)
        #pragma unroll
        for (int n = 0; n < 6; ++n) acc[m][n] = (f4v){0.f,0.f,0.f,0.f};
    const short* kg = kwre + g*9216;
    for (int t = 0; t < 9; ++t){
        s8v A0 = *(const s8v*)(kg + t*1024 + l15*32 + quad*8);
        s8v A1 = *(const s8v*)(kg + t*1024 + (16+l15)*32 + quad*8);
        int pbase = (wave + t/3)*98 + (t%3) + l15;
        #pragma unroll
        for (int n = 0; n < 6; ++n){
            s8v B = *(const s8v*)(xt + (pbase + n*16)*32 + quad*8);
            acc[0][n] = __builtin_amdgcn_mfma_f32_16x16x32_bf16(A0, B, acc[0][n], 0, 0, 0);
            acc[1][n] = __builtin_amdgcn_mfma_f32_16x16x32_bf16(A1, B, acc[1][n], 0, 0, 0);
        }
    }
    int r = r0 + wave;
    #pragma unroll
    for (int m = 0; m < 2; ++m)
        #pragma unroll
        for (int n = 0; n < 6; ++n)
            #pragma unroll
            for (int reg = 0; reg < 4; ++reg){
                int oc = g*32 + m*16 + quad*4 + reg;
                int px = n*16 + l15;
                kout[((size_t)b*CD + oc)*HW + r*WD + px] = f2b(fmaxf(acc[m][n][reg], 0.f));
            }
}

// ---------------- vconv MFMA (fallback path only) ----------------
__global__ void k_vconv_mfma(const void* __restrict__ x, const int* __restrict__ flags,
                             const short* __restrict__ c1wb, bf16* __restrict__ vout){
    __shared__ short xt[96*136];
    int blk = blockIdx.x; int b = blk / 96, r = blk % 96;
    int tid = threadIdx.x;
    bool F = flags[0] != 0;
    for (int idx = tid; idx < 1536; idx += 256){
        int oct = idx / 96, px = idx - oct*96;
        size_t base = ((size_t)b*CD + oct*8)*HW + r*WD + px;
        s8v tmp;
        #pragma unroll
        for (int j = 0; j < 8; ++j){
            float v = F ? ((const float*)x)[base + (size_t)j*HW]
                        : b2f(((const bf16*)x)[base + (size_t)j*HW]);
            tmp[j] = f2bs(v);
        }
        *(s8v*)(xt + px*136 + oct*8) = tmp;
    }
    __syncthreads();
    int wave = tid >> 6, lane = tid & 63, l15 = lane & 15, quad = lane >> 4;
    f4v acc[2][6];
    #pragma unroll
    for (int m = 0; m < 2; ++m)
        #pragma unroll
        for (int n = 0; n < 6; ++n) acc[m][n] = (f4v){0.f,0.f,0.f,0.f};
    for (int k0 = 0; k0 < 128; k0 += 32){
        s8v Bf[6];
        #pragma unroll
        for (int n = 0; n < 6; ++n) Bf[n] = *(const s8v*)(xt + (n*16+l15)*136 + k0 + quad*8);
        #pragma unroll
        for (int m = 0; m < 2; ++m){
            int oc0 = (wave*2 + m)*16;
            s8v A = *(const s8v*)(c1wb + BO_C1W + (oc0 + l15)*128 + k0 + quad*8);
            #pragma unroll
            for (int n = 0; n < 6; ++n)
                acc[m][n] = __builtin_amdgcn_mfma_f32_16x16x32_bf16(A, Bf[n], acc[m][n], 0, 0, 0);
        }
    }
    #pragma unroll
    for (int m = 0; m < 2; ++m)
        #pragma unroll
        for (int n = 0; n < 6; ++n)
            #pragma unroll
            for (int reg = 0; reg < 4; ++reg){
                int oc = (wave*2+m)*16 + quad*4 + reg;
                int px = n*16 + l15;
                vout[((size_t)b*CD + oc)*HW + r*WD + px] = f2b(acc[m][n][reg]);
            }
}

// ================= FAST PATH =================
// embed STATS + fused vconv: stage x-half once, use it for both GEMM1-h1 and the v GEMM.
__global__ void k_embed_stats(const void* __restrict__ x, const int* __restrict__ flags,
                              const bf16* __restrict__ kbuf, const short* __restrict__ canonb,
                              const float* __restrict__ canonf,
                              unsigned short* __restrict__ w1b, bf16* __restrict__ vout,
                              float* __restrict__ gsum_s, float* __restrict__ gsq_s){
    __shared__ short qk[48*136];     // 13056 B, one 128-ch half at a time
    __shared__ short w1s[48*72];     // 6912 B
    __shared__ float gacc[16], gacc2[16];
    const short* ew1b = canonb + BO_EW1;
    const short* ew2b = canonb + BO_EW2;
    const float* eb2f = canonf + CO_EB2;
    int blk = blockIdx.x;
    int px0 = (blk & 1)*48, r = (blk >> 1) % 96, b = blk / 192;
    int tid = threadIdx.x;
    bool F = flags[0] != 0;
    int wave = tid >> 6, lane = tid & 63, l15 = lane & 15, quad = lane >> 4;
    if (tid < 16){ gacc[tid] = 0.f; gacc2[tid] = 0.f; }
    // ---- stage x half (ch 0..127) ----
    for (int idx = tid; idx < 768; idx += 256){
        int oct = idx / 48, px = idx - oct*48;
        size_t base = ((size_t)b*CD + oct*8)*HW + r*WD + px0 + px;
        s8v tmp;
        #pragma unroll
        for (int j = 0; j < 8; ++j){
            float v = F ? ((const float*)x)[base + (size_t)j*HW]
                        : b2f(((const bf16*)x)[base + (size_t)j*HW]);
            tmp[j] = f2bs(v);
        }
        *(s8v*)(qk + px*136 + oct*8) = tmp;
    }
    __syncthreads();
    // ---- GEMM1 half 1 ----
    f4v a1[3];
    #pragma unroll
    for (int n = 0; n < 3; ++n) a1[n] = (f4v){0.f,0.f,0.f,0.f};
    int mb = wave*16;
    for (int k0 = 0; k0 < 128; k0 += 32){
        s8v A = *(const s8v*)(ew1b + (mb + l15)*256 + k0 + quad*8);
        #pragma unroll
        for (int n = 0; n < 3; ++n){
            s8v Bf = *(const s8v*)(qk + (n*16+l15)*136 + k0 + quad*8);
            a1[n] = __builtin_amdgcn_mfma_f32_16x16x32_bf16(A, Bf, a1[n], 0, 0, 0);
        }
    }
    // ---- fused vconv GEMM: v[128 x 48] = C1W[128x128] * X[128x48] ----
    {
        f4v av[2][3];
        #pragma unroll
        for (int m = 0; m < 2; ++m)
            #pragma unroll
            for (int n = 0; n < 3; ++n) av[m][n] = (f4v){0.f,0.f,0.f,0.f};
        for (int k0 = 0; k0 < 128; k0 += 32){
            s8v Bf[3];
            #pragma unroll
            for (int n = 0; n < 3; ++n) Bf[n] = *(const s8v*)(qk + (n*16+l15)*136 + k0 + quad*8);
            #pragma unroll
            for (int m = 0; m < 2; ++m){
                int oc0 = (wave*2 + m)*16;
                s8v A = *(const s8v*)(canonb + BO_C1W + (oc0 + l15)*128 + k0 + quad*8);
                #pragma unroll
                for (int n = 0; n < 3; ++n)
                    av[m][n] = __builtin_amdgcn_mfma_f32_16x16x32_bf16(A, Bf[n], av[m][n], 0, 0, 0);
            }
        }
        #pragma unroll
        for (int m = 0; m < 2; ++m)
            #pragma unroll
            for (int n = 0; n < 3; ++n)
                #pragma unroll
                for (int reg = 0; reg < 4; ++reg){
                    int oc = (wave*2+m)*16 + quad*4 + reg;
                    int px = n*16 + l15;
                    vout[((size_t)b*CD + oc)*HW + r*WD + px0 + px] = f2b(av[m][n][reg]);
                }
    }
    __syncthreads();
    // ---- stage k half (ch 128..255 -> slots 0..127) ----
    {
        const short* kb = (const short*)kbuf;
        for (int idx = tid; idx < 768; idx += 256){
            int oct = idx / 48, px = idx - oct*48;
            size_t base = ((size_t)b*CD + oct*8)*HW + r*WD + px0 + px;
            s8v tmp;
            #pragma unroll
            for (int j = 0; j < 8; ++j) tmp[j] = kb[base + (size_t)j*HW];
            *(s8v*)(qk + px*136 + oct*8) = tmp;
        }
    }
    __syncthreads();
    for (int k0 = 128; k0 < 256; k0 += 32){
        s8v A = *(const s8v*)(ew1b + (mb + l15)*256 + k0 + quad*8);
        #pragma unroll
        for (int n = 0; n < 3; ++n){
            s8v Bf = *(const s8v*)(qk + (n*16+l15)*136 + (k0-128) + quad*8);
            a1[n] = __builtin_amdgcn_mfma_f32_16x16x32_bf16(A, Bf, a1[n], 0, 0, 0);
        }
    }
    #pragma unroll
    for (int n = 0; n < 3; ++n)
        #pragma unroll
        for (int reg = 0; reg < 4; ++reg){
            int ch = mb + quad*4 + reg;
            int px = n*16 + l15;
            w1s[px*72 + ch] = f2bs(fmaxf(a1[n][reg], 0.f));
        }
    __syncthreads();
    size_t gpx0 = (size_t)b*HW + r*WD + px0;
    for (int idx = tid; idx < 768; idx += 256){
        int px = idx >> 4, s4 = idx & 15;
        ushort4 v4 = *(const ushort4*)((const unsigned short*)w1s + px*72 + s4*4);
        *(ushort4*)(w1b + (gpx0 + px)*64 + s4*4) = v4;
    }
    // ---- GEMM2 + frag-level GN moment reduction ----
    {
        f4v a2[3][3];
        #pragma unroll
        for (int i = 0; i < 3; ++i)
            #pragma unroll
            for (int n = 0; n < 3; ++n) a2[i][n] = (f4v){0.f,0.f,0.f,0.f};
        for (int k0 = 0; k0 < 64; k0 += 32){
            s8v Bf[3];
            #pragma unroll
            for (int n = 0; n < 3; ++n) Bf[n] = *(const s8v*)(w1s + (n*16+l15)*72 + k0 + quad*8);
            #pragma unroll
            for (int i = 0; i < 3; ++i){
                int mt = wave + i*4;
                if (mt >= 9) break;
                s8v A = *(const s8v*)(ew2b + (mt*16 + l15)*64 + k0 + quad*8);
                #pragma unroll
                for (int n = 0; n < 3; ++n)
                    a2[i][n] = __builtin_amdgcn_mfma_f32_16x16x32_bf16(A, Bf[n], a2[i][n], 0, 0, 0);
            }
        }
        #pragma unroll
        for (int i = 0; i < 3; ++i){
            int mt = wave + i*4;
            if (mt >= 9) break;
            #pragma unroll
            for (int n = 0; n < 3; ++n)
                #pragma unroll
                for (int reg = 0; reg < 4; ++reg){
                    int o = mt*16 + quad*4 + reg;
                    float v = a2[i][n][reg] + eb2f[o];
                    float s = v, q = v*v;
                    #pragma unroll
                    for (int off = 1; off < 16; off <<= 1){
                        s += __shfl_xor(s, off);
                        q += __shfl_xor(q, off);
                    }
                    if (l15 == 0){
                        int g = o / 9;
                        atomicAdd(&gacc[g], s);
                        atomicAdd(&gacc2[g], q);
                    }
                }
        }
    }
    __syncthreads();
    if (tid < 16){
        int slot = blk & 63;
        atomicAdd(&gsum_s[(b*NG + tid)*64 + slot], gacc[tid]);
        atomicAdd(&gsq_s [(b*NG + tid)*64 + slot], gacc2[tid]);
    }
}

// ---------------- embed APPLY (R8 version — cache-friendly scattered v reads) ----------------
__global__ void k_embed_apply(const unsigned short* __restrict__ w1b,
                              const short* __restrict__ canonb, const float* __restrict__ canonf,
                              const float* __restrict__ gmean, const float* __restrict__ gistd,
                              const bf16* __restrict__ vbuf, float* __restrict__ yout){
    __shared__ short w1s[48*72];     // 6912 B
    __shared__ short w2s[48*146];    // 14016 B, GN-applied
    __shared__ float wsc[WC], wbi[WC];
    const short* ew2b = canonb + BO_EW2;
    const float* eb2f = canonf + CO_EB2;
    int blk = blockIdx.x;
    int px0 = (blk & 1)*48, r = (blk >> 1) % 96, b = blk / 192;
    int tid = threadIdx.x;
    int wave = tid >> 6, lane = tid & 63, l15 = lane & 15, quad = lane >> 4;
    if (tid < WC){
        int g = tid/9;
        float m = gmean[b*NG+g], is = gistd[b*NG+g];
        float ga = canonf[CO_GNG + tid], be = canonf[CO_GNB + tid];
        wsc[tid] = is*ga; wbi[tid] = be - m*is*ga;
    }
    size_t gpx0 = (size_t)b*HW + r*WD + px0;
    for (int idx = tid; idx < 768; idx += 256){
        int px = idx >> 4, s4 = idx & 15;
        ushort4 v4 = *(const ushort4*)(w1b + (gpx0 + px)*64 + s4*4);
        *(ushort4*)((unsigned short*)w1s + px*72 + s4*4) = v4;
    }
    __syncthreads();
    {
        f4v a2[3][3];
        #pragma unroll
        for (int i = 0; i < 3; ++i)
            #pragma unroll
            for (int n = 0; n < 3; ++n) a2[i][n] = (f4v){0.f,0.f,0.f,0.f};
        for (int k0 = 0; k0 < 64; k0 += 32){
            s8v Bf[3];
            #pragma unroll
            for (int n = 0; n < 3; ++n) Bf[n] = *(const s8v*)(w1s + (n*16+l15)*72 + k0 + quad*8);
            #pragma unroll
            for (int i = 0; i < 3; ++i){
                int mt = wave + i*4;
                if (mt >= 9) break;
                s8v A = *(const s8v*)(ew2b + (mt*16 + l15)*64 + k0 + quad*8);
                #pragma unroll
                for (int n = 0; n < 3; ++n)
                    a2[i][n] = __builtin_amdgcn_mfma_f32_16x16x32_bf16(A, Bf[n], a2[i][n], 0, 0, 0);
            }
        }
        #pragma unroll
        for (int i = 0; i < 3; ++i){
            int mt = wave + i*4;
            if (mt >= 9) break;
            #pragma unroll
            for (int n = 0; n < 3; ++n)
                #pragma unroll
                for (int reg = 0; reg < 4; ++reg){
                    int o = mt*16 + quad*4 + reg;
                    int px = n*16 + l15;
                    float val = a2[i][n][reg] + eb2f[o];
                    w2s[px*146 + o] = f2bs(val*wsc[o] + wbi[o]);
                }
        }
    }
    __syncthreads();
    for (int it = tid; it < 6144; it += 256){
        int c = it / 48, px = it - c*48;
        int gcol = px0 + px;
        int g9 = (c >> 3)*9;
        const bf16* vb = vbuf + ((size_t)b*CD + c)*HW;
        float acc = 0.f;
        #pragma unroll
        for (int t = 0; t < 9; ++t){
            int ir = r + t/3 - 1, icc = gcol + t%3 - 1;
            if ((unsigned)ir < 96u && (unsigned)icc < 96u)
                acc += b2f(vb[ir*WD + icc]) * bs2f(w2s[px*146 + g9 + t]);
        }
        yout[((size_t)b*CD + c)*HW + r*WD + gcol] = acc;
    }
}

__global__ void k_bnstat(const float* __restrict__ y, float* __restrict__ bnsum_s,
                         float* __restrict__ bnss_s){
    int blk = blockIdx.x;
    int c = blk >> 4, slice = blk & 15;
    int tid = threadIdx.x;
    float s = 0.f, ss = 0.f;
    int j0 = slice*4608;
    for (int k = 0; k < 18; ++k){
        int j = j0 + k*256 + tid;
        int b = j / HW, p = j - b*HW;
        float v = y[((size_t)b*CD + c)*HW + p];
        s += v; ss += v*v;
    }
    __shared__ float sh[256], sh2[256];
    sh[tid] = s; sh2[tid] = ss;
    __syncthreads();
    for (int st = 128; st > 0; st >>= 1){
        if (tid < st){ sh[tid] += sh[tid+st]; sh2[tid] += sh2[tid+st]; }
        __syncthreads();
    }
    if (tid == 0){
        bnsum_s[c*256 + slice] = sh[0];
        bnss_s [c*256 + slice] = sh2[0];
    }
}

// ================= FALLBACK (R6 embed) =================
template<bool APPLY>
__global__ void k_embed_mfma(const void* __restrict__ x, const int* __restrict__ flags,
                             const bf16* __restrict__ kbuf, const short* __restrict__ canonb,
                             const float* __restrict__ canonf,
                             const float* __restrict__ gmean, const float* __restrict__ gistd,
                             const bf16* __restrict__ vbuf, float* __restrict__ yout,
                             float* __restrict__ gsum_s, float* __restrict__ gsq_s,
                             float* __restrict__ bnsum_s, float* __restrict__ bnss_s){
    __shared__ char buf0[26624];
    __shared__ short w1s[48*72];
    __shared__ short w2s[48*152];
    __shared__ float wsc[WC], wbi[WC];
    __shared__ float blks[256], blkq[256];
    short* qk = (short*)buf0;
    float* yt = (float*)buf0;
    const short* ew1b = canonb + BO_EW1;
    const short* ew2b = canonb + BO_EW2;
    const float* eb2f = canonf + CO_EB2;
    int blk = blockIdx.x;
    int px0 = (blk & 1)*48, r = (blk >> 1) % 96, b = blk / 192;
    int tid = threadIdx.x;
    bool F = flags[0] != 0;
    if (APPLY && tid < WC){
        int g = tid/9;
        float m = gmean[b*NG+g], is = gistd[b*NG+g];
        float ga = canonf[CO_GNG + tid], be = canonf[CO_GNB + tid];
        wsc[tid] = is*ga; wbi[tid] = be - m*is*ga;
    }
    for (int idx = tid; idx < 128*48; idx += 256){
        int c = idx / 48, px = idx - c*48;
        size_t off = ((size_t)b*CD + c)*HW + r*WD + px0 + px;
        float v = F ? ((const float*)x)[off] : b2f(((const bf16*)x)[off]);
        qk[px*264 + c] = f2bs(v);
    }
    for (int idx = tid; idx < 128*48; idx += 256){
        int c = idx / 48, px = idx - c*48;
        qk[px*264 + 128 + c] = ((const short*)kbuf)[((size_t)b*CD + c)*HW + r*WD + px0 + px];
    }
    __syncthreads();
    int wave = tid >> 6, lane = tid & 63, l15 = lane & 15, quad = lane >> 4;
    {
        f4v a1[3];
        #pragma unroll
        for (int n = 0; n < 3; ++n) a1[n] = (f4v){0.f,0.f,0.f,0.f};
        int mb = wave*16;
        for (int k0 = 0; k0 < 256; k0 += 32){
            s8v A = *(const s8v*)(ew1b + (mb + l15)*256 + k0 + quad*8);
            #pragma unroll
            for (int n = 0; n < 3; ++n){
                s8v Bf = *(const s8v*)(qk + (n*16+l15)*264 + k0 + quad*8);
                a1[n] = __builtin_amdgcn_mfma_f32_16x16x32_bf16(A, Bf, a1[n], 0, 0, 0);
            }
        }
        __syncthreads();
        #pragma unroll
        for (int n = 0; n < 3; ++n)
            #pragma unroll
            for (int reg = 0; reg < 4; ++reg){
                int ch = mb + quad*4 + reg;
                int px = n*16 + l15;
                w1s[px*72 + ch] = f2bs(fmaxf(a1[n][reg], 0.f));
            }
    }
    __syncthreads();
    {
        f4v a2[3][3];
        #pragma unroll
        for (int i = 0; i < 3; ++i)
            #pragma unroll
            for (int n = 0; n < 3; ++n) a2[i][n] = (f4v){0.f,0.f,0.f,0.f};
        for (int k0 = 0; k0 < 64; k0 += 32){
            s8v Bf[3];
            #pragma unroll
            for (int n = 0; n < 3; ++n) Bf[n] = *(const s8v*)(w1s + (n*16+l15)*72 + k0 + quad*8);
            #pragma unroll
            for (int i = 0; i < 3; ++i){
                int mt = wave + i*4;
                if (mt >= 9) break;
                s8v A = *(const s8v*)(ew2b + (mt*16 + l15)*64 + k0 + quad*8);
                #pragma unroll
                for (int n = 0; n < 3; ++n)
                    a2[i][n] = __builtin_amdgcn_mfma_f32_16x16x32_bf16(A, Bf[n], a2[i][n], 0, 0, 0);
            }
        }
        #pragma unroll
        for (int i = 0; i < 3; ++i){
            int mt = wave + i*4;
            if (mt >= 9) break;
            #pragma unroll
            for (int n = 0; n < 3; ++n)
                #pragma unroll
                for (int reg = 0; reg < 4; ++reg){
                    int o = mt*16 + quad*4 + reg;
                    int px = n*16 + l15;
                    float val = a2[i][n][reg] + eb2f[o];
                    if (APPLY) val = val*wsc[o] + wbi[o];
                    w2s[px*152 + o] = f2bs(val);
                }
        }
    }
    __syncthreads();
    if (!APPLY){
        if (tid < WC){
            int o = tid; float s = 0.f, ss = 0.f;
            for (int px = 0; px < 48; ++px){ float v = bs2f(w2s[px*152+o]); s += v; ss += v*v; }
            int g = o/9; int slot = blk & 63;
            atomicAdd(&gsum_s[(b*NG+g)*64 + slot], s);
            atomicAdd(&gsq_s [(b*NG+g)*64 + slot], ss);
        }
        return;
    }
    if (tid < 192){
        int px = tid % 48, cq = tid / 48;
        int gcol = px0 + px;
        for (int c = cq*32; c < cq*32 + 32; ++c){
            int g9 = (c >> 3)*9;
            const bf16* vb = vbuf + ((size_t)b*CD + c)*HW;
            float acc = 0.f;
            #pragma unroll
            for (int t = 0; t < 9; ++t){
                int ir = r + t/3 - 1, icc = gcol + t%3 - 1;
                if ((unsigned)ir < 96u && (unsigned)icc < 96u)
                    acc += b2f(vb[ir*WD + icc]) * bs2f(w2s[px*152 + g9 + t]);
            }
            yt[c*52 + px] = acc;
        }
    }
    __syncthreads();
    {
        int c = tid & 127, half = tid >> 7;
        float s = 0.f, ss = 0.f;
        for (int px = half*24; px < half*24 + 24; ++px){
            float v = yt[c*52 + px]; s += v; ss += v*v;
        }
        blks[tid] = s; blkq[tid] = ss;
    }
    __syncthreads();
    if (tid < 128){
        float s = blks[tid] + blks[tid+128];
        float ss = blkq[tid] + blkq[tid+128];
        int slot = blk & 255;
        atomicAdd(&bnsum_s[tid*256 + slot], s);
        atomicAdd(&bnss_s [tid*256 + slot], ss);
    }
    for (int idx = tid; idx < 128*48; idx += 256){
        int c = idx / 48, px = idx - c*48;
        yout[((size_t)b*CD + c)*HW + r*WD + px0 + px] = yt[c*52 + px];
    }
}

// ---------------- GN finalize ----------------
__global__ void k_gnfin(const float* __restrict__ gsum_s, const float* __restrict__ gsq_s,
                        float* __restrict__ gmean, float* __restrict__ gistd){
    int i = threadIdx.x;
    float s = 0.f, ss = 0.f;
    for (int k = 0; k < 64; ++k){ s += gsum_s[i*64 + k]; ss += gsq_s[i*64 + k]; }
    float inv = 1.f / (9.f*HW);
    float m = s*inv;
    float var = ss*inv - m*m;
    gmean[i] = m;
    gistd[i] = rsqrtf(var + 1e-5f);
}

// ---------------- BN finalize ----------------
__global__ void k_bnfin(const float* __restrict__ bnsum_s, const float* __restrict__ bnss_s,
                        const float* __restrict__ canonf,
                        float* __restrict__ scale, float* __restrict__ shift){
    int c = threadIdx.x;
    float s = 0.f, ss = 0.f;
    for (int k = 0; k < 256; ++k){ s += bnsum_s[c*256 + k]; ss += bnss_s[c*256 + k]; }
    float inv = 1.f / (float)(BD*HW);
    float m = s*inv;
    float var = ss*inv - m*m;
    float sc = canonf[CO_BNG + c] * rsqrtf(var + 1e-5f);
    scale[c] = sc;
    shift[c] = canonf[CO_BNB + c] - m*sc;
}

// ---------------- GAP (read-only: swish computed on the fly, y NOT written) ----------------
__global__ void k_gap(const float* __restrict__ ybuf, const bf16* __restrict__ kbuf,
                      const float* __restrict__ scale, const float* __restrict__ shift,
                      float* __restrict__ gap){
    int blk = blockIdx.x;
    int q = blk & 3; int bc = blk >> 2;
    int b = bc / CD, c = bc % CD;
    int tid = threadIdx.x;
    float sc = scale[c], sh = shift[c];
    size_t base = ((size_t)b*CD + c)*HW;
    float gs = 0.f;
    int pend = (q+1)*2304;
    for (int p = q*2304 + tid; p < pend; p += 256){
        float yn = ybuf[base+p] * sc + sh;
        float ys = yn / (1.f + __expf(-yn));
        gs += ys + b2f(kbuf[base+p]);
    }
    __shared__ float shm[256];
    shm[tid] = gs; __syncthreads();
    for (int st = 128; st > 0; st >>= 1){
        if (tid < st) shm[tid] += shm[tid+st];
        __syncthreads();
    }
    if (tid == 0) atomicAdd(&gap[b*CD+c], shm[0]);
}

// ---------------- SE ----------------
__global__ void k_se(const float* __restrict__ gap, const float* __restrict__ canonf,
                     float* __restrict__ p0, float* __restrict__ p1){
    int b = blockIdx.x;
    int tid = threadIdx.x;
    __shared__ float loc[128], h1[64];
    float invhw = 1.f / (float)HW;
    loc[tid]      = gap[b*CD + tid]      * invhw;
    loc[tid + 64] = gap[b*CD + tid + 64] * invhw;
    __syncthreads();
    {
        const float* wr = canonf + CO_SW1 + (size_t)tid*128;
        float acc = canonf[CO_SB1 + tid];
        for (int c = 0; c < 128; ++c) acc += wr[c] * loc[c];
        h1[tid] = fmaxf(acc, 0.f);
    }
    __syncthreads();
    for (int c = tid; c < 128; c += 64){
        float a0 = canonf[CO_SB2 + 2*c], a1 = canonf[CO_SB2 + 2*c+1];
        const float* w0 = canonf + CO_SW2 + (size_t)(2*c)*64;
        const float* w1p = canonf + CO_SW2 + (size_t)(2*c+1)*64;
        for (int j = 0; j < 64; ++j){
            a0 += w0[j] * h1[j];
            a1 += w1p[j] * h1[j];
        }
        float mx = fmaxf(a0, a1);
        float e0 = __expf(a0-mx), e1 = __expf(a1-mx);
        float inv = 1.f / (e0 + e1);
        p0[b*CD+c] = e0*inv;
        p1[b*CD+c] = e1*inv;
    }
}

// ---------------- out: recompute BN+swish from raw y, blend, write (in-place) ----------------
__global__ void k_out(float* __restrict__ ybuf, const bf16* __restrict__ kbuf,
                      const float* __restrict__ scale, const float* __restrict__ shift,
                      const float* __restrict__ p0, const float* __restrict__ p1){
    size_t idx = (size_t)blockIdx.x*256 + threadIdx.x;
    if (idx >= NTOT) return;
    int bc = (int)(idx / HW);
    int c = bc % CD, b = bc / CD;
    float yn = ybuf[idx]*scale[c] + shift[c];
    float ys = yn / (1.f + __expf(-yn));
    ybuf[idx] = ys*p0[b*CD+c] + b2f(kbuf[idx])*p1[b*CD+c];
}

extern "C" void kernel_launch(void* const* d_in, const int* in_sizes, int n_in,
                              void* d_out, int out_size, void* d_ws, size_t ws_size,
                              hipStream_t stream) {
    TensPtrs tp;
    for (int i = 0; i < 14; ++i) tp.p[i] = d_in[i];

    float* f = (float*)d_ws;
    float* bnsum_s = f;            // 32768 (zeroed)
    float* bnss_s  = f + 32768;    // 32768 (zeroed)
    float* gsum_s  = f + 65536;    // 8192  (zeroed)
    float* gsq_s   = f + 73728;    // 8192  (zeroed)
    float* gap     = f + 81920;    // 1024  (zeroed)
    float* gmean   = f + 82944;
    float* gistd   = f + 83072;
    float* bscale  = f + 83200;
    float* bshift  = f + 83328;
    float* p0      = f + 83456;
    float* p1      = f + 84480;
    int*   flags = (int*)((char*)d_ws + 393216);
    float* canonf = (float*)((char*)d_ws + 425984);
    short* canonb = (short*)((char*)d_ws + 860160);
    bf16*  kbuf  = (bf16*)((char*)d_ws + 1048576);        // 18.87 MB
    bf16*  vbuf  = kbuf + NTOT;                           // 18.87 MB (ends 38,797,312)
    unsigned short* w1b = (unsigned short*)((char*)d_ws + 38797312);  // 9.44 MB (ends 48,234,496)
    float* ybuf  = (float*)d_out;
    short* kwre = (short*)((char*)d_out + KWRE_OFF);      // scratch in d_out, overwritten by y

    bool fast = ws_size >= 48234496ull;

    k_detect<<<14, 64, 0, stream>>>(tp, flags);
    k_canon<<<13, 256, 0, stream>>>(tp, flags, canonf, canonb);
    k_reorder_kw<<<144, 256, 0, stream>>>(canonb, kwre);
    k_zero<<<324, 256, 0, stream>>>(f, 82944);
    k_keyconv_mfma<<<768, 256, 0, stream>>>(d_in[0], flags, kwre, kbuf);
    if (fast){
        k_embed_stats<<<1536, 256, 0, stream>>>(d_in[0], flags, kbuf, canonb, canonf,
                                                w1b, vbuf, gsum_s, gsq_s);
        k_gnfin<<<1, 128, 0, stream>>>(gsum_s, gsq_s, gmean, gistd);
        k_embed_apply<<<1536, 256, 0, stream>>>(w1b, canonb, canonf, gmean, gistd,
                                                vbuf, ybuf);
        k_bnstat<<<2048, 256, 0, stream>>>(ybuf, bnsum_s, bnss_s);
    } else {
        k_embed_mfma<false><<<1536, 256, 0, stream>>>(d_in[0], flags, kbuf, canonb, canonf,
                                                      gmean, gistd, vbuf, ybuf,
                                                      gsum_s, gsq_s, bnsum_s, bnss_s);
        k_gnfin<<<1, 128, 0, stream>>>(gsum_s, gsq_s, gmean, gistd);
        k_vconv_mfma<<<768, 256, 0, stream>>>(d_in[0], flags, canonb, vbuf);
        k_embed_mfma<true><<<1536, 256, 0, stream>>>(d_in[0], flags, kbuf, canonb, canonf,
                                                     gmean, gistd, vbuf, ybuf,
                                                     gsum_s, gsq_s, bnsum_s, bnss_s);
    }
    k_bnfin<<<1, 128, 0, stream>>>(bnsum_s, bnss_s, canonf, bscale, bshift);
    k_gap<<<BD*CD*4, 256, 0, stream>>>(ybuf, kbuf, bscale, bshift, gap);
    k_se<<<BD, 64, 0, stream>>>(gap, canonf, p0, p1);
    k_out<<<(int)((NTOT + 255)/256), 256, 0, stream>>>(ybuf, kbuf, bscale, bshift, p0, p1);
}

// Round 11
// 357.779 us; speedup vs baseline: 1.2143x; 1.0830x over previous
//
#include <hip/hip_runtime.h>
#include <hip/hip_bf16.h>

#define BD 8
#define CD 128
#define HD 96
#define WD 96
#define HW (HD*WD)          // 9216
#define NPIX (BD*HW)        // 73728
#define NTOT ((size_t)BD*CD*HW) // 9437184
#define WC 144
#define NG 16
#define KWRE_OFF 37617664   // scratch inside d_out (y overwrites it later)
// xb16 (bf16 x) lives at d_out[0 .. 18.9MB) during the front half; y overwrites later.

typedef __hip_bfloat16 bf16;
typedef __attribute__((ext_vector_type(8))) short s8v;   // 8 bf16 (A/B frag)
typedef __attribute__((ext_vector_type(4))) float f4v;   // 4 f32 (C/D frag)

__device__ __forceinline__ float b2f(bf16 v){ return __bfloat162float(v); }
__device__ __forceinline__ bf16  f2b(float v){ return __float2bfloat16(v); }
__device__ __forceinline__ short f2bs(float f){ union{ bf16 h; short s; } u; u.h = f2b(f); return u.s; }
__device__ __forceinline__ float bs2f(short s){ union{ bf16 h; short s; } u; u.s = s; return b2f(u.h); }

struct TensPtrs { const void* p[14]; };

__device__ __constant__ int dNelem[14] = {
    9437184, 36864, 16384, 9216, 144, 144, 144, 16384, 128, 128, 8192, 64, 16384, 256
};
__device__ __constant__ int dCanonOff[14] = {
    0, 0, 36864, 53248, 62464, 62608, 62752, 62896, 79280, 79408, 79536, 87728, 87792, 104176
};
__device__ __constant__ int dBOff[14] = {
    -1, 0, 36864, 53248, -1, -1, -1, 62464, -1, -1, -1, -1, -1, -1
};
#define CO_EB2  62464
#define CO_GNG  62608
#define CO_GNB  62752
#define CO_BNG  79280
#define CO_BNB  79408
#define CO_SW1  79536
#define CO_SB1  87728
#define CO_SW2  87792
#define CO_SB2  104176
#define BO_KW   0
#define BO_EW1  36864
#define BO_EW2  53248
#define BO_C1W  62464

// ---------------- detect ----------------
__global__ void k_detect(TensPtrs tp, int* __restrict__ flags){
    int i = blockIdx.x; int tid = threadIdx.x;
    int n = dNelem[i];
    int m = n < 4096 ? n : 4096;
    int pairs = m >> 1;
    const unsigned short* u = (const unsigned short*)tp.p[i];
    int v = 0;
    for (int j = tid; j < pairs; j += 64){
        unsigned short lo = u[2*j], hi = u[2*j+1];
        int e = (lo >> 7) & 0xFF;
        bool wild = (e >= 0xBE) || (e > 0 && e < 0x40);
        if (wild || (lo == 0 && hi != 0)) v++;
    }
    __shared__ int sv[64];
    sv[tid] = v; __syncthreads();
    for (int st = 32; st > 0; st >>= 1){
        if (tid < st) sv[tid] += sv[tid+st];
        __syncthreads();
    }
    if (tid == 0) flags[i] = (sv[0]*8 > pairs) ? 1 : 0;
}

// ---------------- canon ----------------
__global__ void k_canon(TensPtrs tp, const int* __restrict__ flags,
                        float* __restrict__ canonf, short* __restrict__ canonb){
    int i = blockIdx.x + 1;
    int n = dNelem[i]; int off = dCanonOff[i]; int bo = dBOff[i];
    bool f32 = flags[i] != 0;
    for (int j = threadIdx.x; j < n; j += 256){
        float v = f32 ? ((const float*)tp.p[i])[j] : b2f(((const bf16*)tp.p[i])[j]);
        canonf[off + j] = v;
        if (bo >= 0) canonb[bo + j] = f2bs(v);
    }
}

// ---------------- xcast: x (f32 or bf16) -> bf16, 4 elems/thread ----------------
__global__ void k_xcast(const void* __restrict__ x, const int* __restrict__ flags,
                        unsigned short* __restrict__ xb){
    size_t i = (size_t)blockIdx.x*256 + threadIdx.x;   // vec4 index, NTOT/4 total
    if (flags[0]){
        float4 v = ((const float4*)x)[i];
        ushort4 o;
        o.x = (unsigned short)f2bs(v.x); o.y = (unsigned short)f2bs(v.y);
        o.z = (unsigned short)f2bs(v.z); o.w = (unsigned short)f2bs(v.w);
        ((ushort4*)xb)[i] = o;
    } else {
        ((ushort4*)xb)[i] = ((const ushort4*)x)[i];
    }
}

// ---------------- reorder key weights: [g][oc][ic][t] -> [g][t][oc][ic] ----------------
__global__ void k_reorder_kw(const short* __restrict__ canonb, short* __restrict__ kwre){
    int idx = blockIdx.x*256 + threadIdx.x;   // 36864
    if (idx >= 36864) return;
    int g = idx / 9216, rem = idx - g*9216;
    int oc = rem / 288, r2 = rem - oc*288;
    int ic = r2 / 9, t = r2 - ic*9;
    kwre[g*9216 + t*1024 + oc*32 + ic] = canonb[BO_KW + idx];
}

__global__ void k_zero(float* __restrict__ p, int n){
    int i = blockIdx.x*256 + threadIdx.x;
    if (i < n) p[i] = 0.f;
}

// ---------------- keyconv MFMA (reads bf16 x) ----------------
__global__ void k_keyconv_mfma(const short* __restrict__ xb,
                               const short* __restrict__ kwre, bf16* __restrict__ kout){
    __shared__ short xt[588*32];     // [pixel(6x98)][ic] 37632 B
    int blk = blockIdx.x;
    int band = blk % 24, g = (blk/24) & 3, b = blk / 96;
    int r0 = band*4;
    int tid = threadIdx.x;
    for (int idx = tid; idx < 2352; idx += 256){
        int oct = idx / 588, pxl = idx - oct*588;
        int pr = pxl / 98, pc = pxl - pr*98;
        int ir = r0 - 1 + pr, icol = pc - 1;
        bool inb = ((unsigned)ir < 96u) & ((unsigned)icol < 96u);
        size_t base = ((size_t)b*CD + g*32 + oct*8)*HW + ir*WD + icol;
        s8v tmp;
        #pragma unroll
        for (int j = 0; j < 8; ++j){
            short v = 0;
            if (inb) v = xb[base + (size_t)j*HW];
            tmp[j] = v;
        }
        *(s8v*)(xt + pxl*32 + oct*8) = tmp;
    }
    __syncthreads();
    int wave = tid >> 6, lane = tid & 63, l15 = lane & 15, quad = lane >> 4;
    f4v acc[2][6];
    #pragma unroll
    for (int m = 0; m < 2; ++m)
        #pragma unroll
        for (int n = 0; n < 6; ++n) acc[m][n] = (f4v){0.f,0.f,0.f,0.f};
    const short* kg = kwre + g*9216;
    for (int t = 0; t < 9; ++t){
        s8v A0 = *(const s8v*)(kg + t*1024 + l15*32 + quad*8);
        s8v A1 = *(const s8v*)(kg + t*1024 + (16+l15)*32 + quad*8);
        int pbase = (wave + t/3)*98 + (t%3) + l15;
        #pragma unroll
        for (int n = 0; n < 6; ++n){
            s8v B = *(const s8v*)(xt + (pbase + n*16)*32 + quad*8);
            acc[0][n] = __builtin_amdgcn_mfma_f32_16x16x32_bf16(A0, B, acc[0][n], 0, 0, 0);
            acc[1][n] = __builtin_amdgcn_mfma_f32_16x16x32_bf16(A1, B, acc[1][n], 0, 0, 0);
        }
    }
    int r = r0 + wave;
    #pragma unroll
    for (int m = 0; m < 2; ++m)
        #pragma unroll
        for (int n = 0; n < 6; ++n)
            #pragma unroll
            for (int reg = 0; reg < 4; ++reg){
                int oc = g*32 + m*16 + quad*4 + reg;
                int px = n*16 + l15;
                kout[((size_t)b*CD + oc)*HW + r*WD + px] = f2b(fmaxf(acc[m][n][reg], 0.f));
            }
}

// ---------------- vconv MFMA (fallback path only) ----------------
__global__ void k_vconv_mfma(const void* __restrict__ x, const int* __restrict__ flags,
                             const short* __restrict__ c1wb, bf16* __restrict__ vout){
    __shared__ short xt[96*136];
    int blk = blockIdx.x; int b = blk / 96, r = blk % 96;
    int tid = threadIdx.x;
    bool F = flags[0] != 0;
    for (int idx = tid; idx < 1536; idx += 256){
        int oct = idx / 96, px = idx - oct*96;
        size_t base = ((size_t)b*CD + oct*8)*HW + r*WD + px;
        s8v tmp;
        #pragma unroll
        for (int j = 0; j < 8; ++j){
            float v = F ? ((const float*)x)[base + (size_t)j*HW]
                        : b2f(((const bf16*)x)[base + (size_t)j*HW]);
            tmp[j] = f2bs(v);
        }
        *(s8v*)(xt + px*136 + oct*8) = tmp;
    }
    __syncthreads();
    int wave = tid >> 6, lane = tid & 63, l15 = lane & 15, quad = lane >> 4;
    f4v acc[2][6];
    #pragma unroll
    for (int m = 0; m < 2; ++m)
        #pragma unroll
        for (int n = 0; n < 6; ++n) acc[m][n] = (f4v){0.f,0.f,0.f,0.f};
    for (int k0 = 0; k0 < 128; k0 += 32){
        s8v Bf[6];
        #pragma unroll
        for (int n = 0; n < 6; ++n) Bf[n] = *(const s8v*)(xt + (n*16+l15)*136 + k0 + quad*8);
        #pragma unroll
        for (int m = 0; m < 2; ++m){
            int oc0 = (wave*2 + m)*16;
            s8v A = *(const s8v*)(c1wb + BO_C1W + (oc0 + l15)*128 + k0 + quad*8);
            #pragma unroll
            for (int n = 0; n < 6; ++n)
                acc[m][n] = __builtin_amdgcn_mfma_f32_16x16x32_bf16(A, Bf[n], acc[m][n], 0, 0, 0);
        }
    }
    #pragma unroll
    for (int m = 0; m < 2; ++m)
        #pragma unroll
        for (int n = 0; n < 6; ++n)
            #pragma unroll
            for (int reg = 0; reg < 4; ++reg){
                int oc = (wave*2+m)*16 + quad*4 + reg;
                int px = n*16 + l15;
                vout[((size_t)b*CD + oc)*HW + r*WD + px] = f2b(acc[m][n][reg]);
            }
}

// ================= FAST PATH =================
// embed STATS + fused vconv (reads bf16 x)
__global__ void k_embed_stats(const short* __restrict__ xb,
                              const bf16* __restrict__ kbuf, const short* __restrict__ canonb,
                              const float* __restrict__ canonf,
                              unsigned short* __restrict__ w1b, bf16* __restrict__ vout,
                              float* __restrict__ gsum_s, float* __restrict__ gsq_s){
    __shared__ short qk[48*136];     // 13056 B, one 128-ch half at a time
    __shared__ short w1s[48*72];     // 6912 B
    __shared__ float gacc[16], gacc2[16];
    const short* ew1b = canonb + BO_EW1;
    const short* ew2b = canonb + BO_EW2;
    const float* eb2f = canonf + CO_EB2;
    int blk = blockIdx.x;
    int px0 = (blk & 1)*48, r = (blk >> 1) % 96, b = blk / 192;
    int tid = threadIdx.x;
    int wave = tid >> 6, lane = tid & 63, l15 = lane & 15, quad = lane >> 4;
    if (tid < 16){ gacc[tid] = 0.f; gacc2[tid] = 0.f; }
    // ---- stage x half (ch 0..127) ----
    for (int idx = tid; idx < 768; idx += 256){
        int oct = idx / 48, px = idx - oct*48;
        size_t base = ((size_t)b*CD + oct*8)*HW + r*WD + px0 + px;
        s8v tmp;
        #pragma unroll
        for (int j = 0; j < 8; ++j) tmp[j] = xb[base + (size_t)j*HW];
        *(s8v*)(qk + px*136 + oct*8) = tmp;
    }
    __syncthreads();
    // ---- GEMM1 half 1 ----
    f4v a1[3];
    #pragma unroll
    for (int n = 0; n < 3; ++n) a1[n] = (f4v){0.f,0.f,0.f,0.f};
    int mb = wave*16;
    for (int k0 = 0; k0 < 128; k0 += 32){
        s8v A = *(const s8v*)(ew1b + (mb + l15)*256 + k0 + quad*8);
        #pragma unroll
        for (int n = 0; n < 3; ++n){
            s8v Bf = *(const s8v*)(qk + (n*16+l15)*136 + k0 + quad*8);
            a1[n] = __builtin_amdgcn_mfma_f32_16x16x32_bf16(A, Bf, a1[n], 0, 0, 0);
        }
    }
    // ---- fused vconv GEMM: v[128 x 48] = C1W[128x128] * X[128x48] ----
    {
        f4v av[2][3];
        #pragma unroll
        for (int m = 0; m < 2; ++m)
            #pragma unroll
            for (int n = 0; n < 3; ++n) av[m][n] = (f4v){0.f,0.f,0.f,0.f};
        for (int k0 = 0; k0 < 128; k0 += 32){
            s8v Bf[3];
            #pragma unroll
            for (int n = 0; n < 3; ++n) Bf[n] = *(const s8v*)(qk + (n*16+l15)*136 + k0 + quad*8);
            #pragma unroll
            for (int m = 0; m < 2; ++m){
                int oc0 = (wave*2 + m)*16;
                s8v A = *(const s8v*)(canonb + BO_C1W + (oc0 + l15)*128 + k0 + quad*8);
                #pragma unroll
                for (int n = 0; n < 3; ++n)
                    av[m][n] = __builtin_amdgcn_mfma_f32_16x16x32_bf16(A, Bf[n], av[m][n], 0, 0, 0);
            }
        }
        #pragma unroll
        for (int m = 0; m < 2; ++m)
            #pragma unroll
            for (int n = 0; n < 3; ++n)
                #pragma unroll
                for (int reg = 0; reg < 4; ++reg){
                    int oc = (wave*2+m)*16 + quad*4 + reg;
                    int px = n*16 + l15;
                    vout[((size_t)b*CD + oc)*HW + r*WD + px0 + px] = f2b(av[m][n][reg]);
                }
    }
    __syncthreads();
    // ---- stage k half (ch 128..255 -> slots 0..127) ----
    {
        const short* kb = (const short*)kbuf;
        for (int idx = tid; idx < 768; idx += 256){
            int oct = idx / 48, px = idx - oct*48;
            size_t base = ((size_t)b*CD + oct*8)*HW + r*WD + px0 + px;
            s8v tmp;
            #pragma unroll
            for (int j = 0; j < 8; ++j) tmp[j] = kb[base + (size_t)j*HW];
            *(s8v*)(qk + px*136 + oct*8) = tmp;
        }
    }
    __syncthreads();
    for (int k0 = 128; k0 < 256; k0 += 32){
        s8v A = *(const s8v*)(ew1b + (mb + l15)*256 + k0 + quad*8);
        #pragma unroll
        for (int n = 0; n < 3; ++n){
            s8v Bf = *(const s8v*)(qk + (n*16+l15)*136 + (k0-128) + quad*8);
            a1[n] = __builtin_amdgcn_mfma_f32_16x16x32_bf16(A, Bf, a1[n], 0, 0, 0);
        }
    }
    #pragma unroll
    for (int n = 0; n < 3; ++n)
        #pragma unroll
        for (int reg = 0; reg < 4; ++reg){
            int ch = mb + quad*4 + reg;
            int px = n*16 + l15;
            w1s[px*72 + ch] = f2bs(fmaxf(a1[n][reg], 0.f));
        }
    __syncthreads();
    size_t gpx0 = (size_t)b*HW + r*WD + px0;
    for (int idx = tid; idx < 768; idx += 256){
        int px = idx >> 4, s4 = idx & 15;
        ushort4 v4 = *(const ushort4*)((const unsigned short*)w1s + px*72 + s4*4);
        *(ushort4*)(w1b + (gpx0 + px)*64 + s4*4) = v4;
    }
    // ---- GEMM2 + frag-level GN moment reduction ----
    {
        f4v a2[3][3];
        #pragma unroll
        for (int i = 0; i < 3; ++i)
            #pragma unroll
            for (int n = 0; n < 3; ++n) a2[i][n] = (f4v){0.f,0.f,0.f,0.f};
        for (int k0 = 0; k0 < 64; k0 += 32){
            s8v Bf[3];
            #pragma unroll
            for (int n = 0; n < 3; ++n) Bf[n] = *(const s8v*)(w1s + (n*16+l15)*72 + k0 + quad*8);
            #pragma unroll
            for (int i = 0; i < 3; ++i){
                int mt = wave + i*4;
                if (mt >= 9) break;
                s8v A = *(const s8v*)(ew2b + (mt*16 + l15)*64 + k0 + quad*8);
                #pragma unroll
                for (int n = 0; n < 3; ++n)
                    a2[i][n] = __builtin_amdgcn_mfma_f32_16x16x32_bf16(A, Bf[n], a2[i][n], 0, 0, 0);
            }
        }
        #pragma unroll
        for (int i = 0; i < 3; ++i){
            int mt = wave + i*4;
            if (mt >= 9) break;
            #pragma unroll
            for (int n = 0; n < 3; ++n)
                #pragma unroll
                for (int reg = 0; reg < 4; ++reg){
                    int o = mt*16 + quad*4 + reg;
                    float v = a2[i][n][reg] + eb2f[o];
                    float s = v, q = v*v;
                    #pragma unroll
                    for (int off = 1; off < 16; off <<= 1){
                        s += __shfl_xor(s, off);
                        q += __shfl_xor(q, off);
                    }
                    if (l15 == 0){
                        int g = o / 9;
                        atomicAdd(&gacc[g], s);
                        atomicAdd(&gacc2[g], q);
                    }
                }
        }
    }
    __syncthreads();
    if (tid < 16){
        int slot = blk & 63;
        atomicAdd(&gsum_s[(b*NG + tid)*64 + slot], gacc[tid]);
        atomicAdd(&gsq_s [(b*NG + tid)*64 + slot], gacc2[tid]);
    }
}

// ---------------- embed APPLY (R8 version — cache-friendly scattered v reads) ----------------
__global__ void k_embed_apply(const unsigned short* __restrict__ w1b,
                              const short* __restrict__ canonb, const float* __restrict__ canonf,
                              const float* __restrict__ gmean, const float* __restrict__ gistd,
                              const bf16* __restrict__ vbuf, float* __restrict__ yout){
    __shared__ short w1s[48*72];     // 6912 B
    __shared__ short w2s[48*146];    // 14016 B, GN-applied
    __shared__ float wsc[WC], wbi[WC];
    const short* ew2b = canonb + BO_EW2;
    const float* eb2f = canonf + CO_EB2;
    int blk = blockIdx.x;
    int px0 = (blk & 1)*48, r = (blk >> 1) % 96, b = blk / 192;
    int tid = threadIdx.x;
    int wave = tid >> 6, lane = tid & 63, l15 = lane & 15, quad = lane >> 4;
    if (tid < WC){
        int g = tid/9;
        float m = gmean[b*NG+g], is = gistd[b*NG+g];
        float ga = canonf[CO_GNG + tid], be = canonf[CO_GNB + tid];
        wsc[tid] = is*ga; wbi[tid] = be - m*is*ga;
    }
    size_t gpx0 = (size_t)b*HW + r*WD + px0;
    for (int idx = tid; idx < 768; idx += 256){
        int px = idx >> 4, s4 = idx & 15;
        ushort4 v4 = *(const ushort4*)(w1b + (gpx0 + px)*64 + s4*4);
        *(ushort4*)((unsigned short*)w1s + px*72 + s4*4) = v4;
    }
    __syncthreads();
    {
        f4v a2[3][3];
        #pragma unroll
        for (int i = 0; i < 3; ++i)
            #pragma unroll
            for (int n = 0; n < 3; ++n) a2[i][n] = (f4v){0.f,0.f,0.f,0.f};
        for (int k0 = 0; k0 < 64; k0 += 32){
            s8v Bf[3];
            #pragma unroll
            for (int n = 0; n < 3; ++n) Bf[n] = *(const s8v*)(w1s + (n*16+l15)*72 + k0 + quad*8);
            #pragma unroll
            for (int i = 0; i < 3; ++i){
                int mt = wave + i*4;
                if (mt >= 9) break;
                s8v A = *(const s8v*)(ew2b + (mt*16 + l15)*64 + k0 + quad*8);
                #pragma unroll
                for (int n = 0; n < 3; ++n)
                    a2[i][n] = __builtin_amdgcn_mfma_f32_16x16x32_bf16(A, Bf[n], a2[i][n], 0, 0, 0);
            }
        }
        #pragma unroll
        for (int i = 0; i < 3; ++i){
            int mt = wave + i*4;
            if (mt >= 9) break;
            #pragma unroll
            for (int n = 0; n < 3; ++n)
                #pragma unroll
                for (int reg = 0; reg < 4; ++reg){
                    int o = mt*16 + quad*4 + reg;
                    int px = n*16 + l15;
                    float val = a2[i][n][reg] + eb2f[o];
                    w2s[px*146 + o] = f2bs(val*wsc[o] + wbi[o]);
                }
        }
    }
    __syncthreads();
    for (int it = tid; it < 6144; it += 256){
        int c = it / 48, px = it - c*48;
        int gcol = px0 + px;
        int g9 = (c >> 3)*9;
        const bf16* vb = vbuf + ((size_t)b*CD + c)*HW;
        float acc = 0.f;
        #pragma unroll
        for (int t = 0; t < 9; ++t){
            int ir = r + t/3 - 1, icc = gcol + t%3 - 1;
            if ((unsigned)ir < 96u && (unsigned)icc < 96u)
                acc += b2f(vb[ir*WD + icc]) * bs2f(w2s[px*146 + g9 + t]);
        }
        yout[((size_t)b*CD + c)*HW + r*WD + gcol] = acc;
    }
}

// ---------------- BN stats from y (float4, 8 slices/channel) ----------------
__global__ void k_bnstat(const float* __restrict__ y, float* __restrict__ bnsum_s,
                         float* __restrict__ bnss_s){
    int blk = blockIdx.x;            // 1024 = 128c x 8 slices
    int c = blk >> 3, slice = blk & 7;
    int tid = threadIdx.x;
    const float4* y4 = (const float4*)y;
    float s = 0.f, ss = 0.f;
    int i0 = slice*2304;             // vec4 index within 18432 per channel
    for (int k = 0; k < 9; ++k){
        int i = i0 + k*256 + tid;    // i in [0, 18432)
        int b = i / 2304, p4 = i - b*2304;
        float4 v = y4[(size_t)(b*CD + c)*2304 + p4];
        s += v.x + v.y + v.z + v.w;
        ss += v.x*v.x + v.y*v.y + v.z*v.z + v.w*v.w;
    }
    __shared__ float sh[256], sh2[256];
    sh[tid] = s; sh2[tid] = ss;
    __syncthreads();
    for (int st = 128; st > 0; st >>= 1){
        if (tid < st){ sh[tid] += sh[tid+st]; sh2[tid] += sh2[tid+st]; }
        __syncthreads();
    }
    if (tid == 0){
        bnsum_s[c*256 + slice] = sh[0];
        bnss_s [c*256 + slice] = sh2[0];
    }
}

// ================= FALLBACK (R6 embed) =================
template<bool APPLY>
__global__ void k_embed_mfma(const void* __restrict__ x, const int* __restrict__ flags,
                             const bf16* __restrict__ kbuf, const short* __restrict__ canonb,
                             const float* __restrict__ canonf,
                             const float* __restrict__ gmean, const float* __restrict__ gistd,
                             const bf16* __restrict__ vbuf, float* __restrict__ yout,
                             float* __restrict__ gsum_s, float* __restrict__ gsq_s,
                             float* __restrict__ bnsum_s, float* __restrict__ bnss_s){
    __shared__ char buf0[26624];
    __shared__ short w1s[48*72];
    __shared__ short w2s[48*152];
    __shared__ float wsc[WC], wbi[WC];
    __shared__ float blks[256], blkq[256];
    short* qk = (short*)buf0;
    float* yt = (float*)buf0;
    const short* ew1b = canonb + BO_EW1;
    const short* ew2b = canonb + BO_EW2;
    const float* eb2f = canonf + CO_EB2;
    int blk = blockIdx.x;
    int px0 = (blk & 1)*48, r = (blk >> 1) % 96, b = blk / 192;
    int tid = threadIdx.x;
    bool F = flags[0] != 0;
    if (APPLY && tid < WC){
        int g = tid/9;
        float m = gmean[b*NG+g], is = gistd[b*NG+g];
        float ga = canonf[CO_GNG + tid], be = canonf[CO_GNB + tid];
        wsc[tid] = is*ga; wbi[tid] = be - m*is*ga;
    }
    for (int idx = tid; idx < 128*48; idx += 256){
        int c = idx / 48, px = idx - c*48;
        size_t off = ((size_t)b*CD + c)*HW + r*WD + px0 + px;
        float v = F ? ((const float*)x)[off] : b2f(((const bf16*)x)[off]);
        qk[px*264 + c] = f2bs(v);
    }
    for (int idx = tid; idx < 128*48; idx += 256){
        int c = idx / 48, px = idx - c*48;
        qk[px*264 + 128 + c] = ((const short*)kbuf)[((size_t)b*CD + c)*HW + r*WD + px0 + px];
    }
    __syncthreads();
    int wave = tid >> 6, lane = tid & 63, l15 = lane & 15, quad = lane >> 4;
    {
        f4v a1[3];
        #pragma unroll
        for (int n = 0; n < 3; ++n) a1[n] = (f4v){0.f,0.f,0.f,0.f};
        int mb = wave*16;
        for (int k0 = 0; k0 < 256; k0 += 32){
            s8v A = *(const s8v*)(ew1b + (mb + l15)*256 + k0 + quad*8);
            #pragma unroll
            for (int n = 0; n < 3; ++n){
                s8v Bf = *(const s8v*)(qk + (n*16+l15)*264 + k0 + quad*8);
                a1[n] = __builtin_amdgcn_mfma_f32_16x16x32_bf16(A, Bf, a1[n], 0, 0, 0);
            }
        }
        __syncthreads();
        #pragma unroll
        for (int n = 0; n < 3; ++n)
            #pragma unroll
            for (int reg = 0; reg < 4; ++reg){
                int ch = mb + quad*4 + reg;
                int px = n*16 + l15;
                w1s[px*72 + ch] = f2bs(fmaxf(a1[n][reg], 0.f));
            }
    }
    __syncthreads();
    {
        f4v a2[3][3];
        #pragma unroll
        for (int i = 0; i < 3; ++i)
            #pragma unroll
            for (int n = 0; n < 3; ++n) a2[i][n] = (f4v){0.f,0.f,0.f,0.f};
        for (int k0 = 0; k0 < 64; k0 += 32){
            s8v Bf[3];
            #pragma unroll
            for (int n = 0; n < 3; ++n) Bf[n] = *(const s8v*)(w1s + (n*16+l15)*72 + k0 + quad*8);
            #pragma unroll
            for (int i = 0; i < 3; ++i){
                int mt = wave + i*4;
                if (mt >= 9) break;
                s8v A = *(const s8v*)(ew2b + (mt*16 + l15)*64 + k0 + quad*8);
                #pragma unroll
                for (int n = 0; n < 3; ++n)
                    a2[i][n] = __builtin_amdgcn_mfma_f32_16x16x32_bf16(A, Bf[n], a2[i][n], 0, 0, 0);
            }
        }
        #pragma unroll
        for (int i = 0; i < 3; ++i){
            int mt = wave + i*4;
            if (mt >= 9) break;
            #pragma unroll
            for (int n = 0; n < 3; ++n)
                #pragma unroll
                for (int reg = 0; reg < 4; ++reg){
                    int o = mt*16 + quad*4 + reg;
                    int px = n*16 + l15;
                    float val = a2[i][n][reg] + eb2f[o];
                    if (APPLY) val = val*wsc[o] + wbi[o];
                    w2s[px*152 + o] = f2bs(val);
                }
        }
    }
    __syncthreads();
    if (!APPLY){
        if (tid < WC){
            int o = tid; float s = 0.f, ss = 0.f;
            for (int px = 0; px < 48; ++px){ float v = bs2f(w2s[px*152+o]); s += v; ss += v*v; }
            int g = o/9; int slot = blk & 63;
            atomicAdd(&gsum_s[(b*NG+g)*64 + slot], s);
            atomicAdd(&gsq_s [(b*NG+g)*64 + slot], ss);
        }
        return;
    }
    if (tid < 192){
        int px = tid % 48, cq = tid / 48;
        int gcol = px0 + px;
        for (int c = cq*32; c < cq*32 + 32; ++c){
            int g9 = (c >> 3)*9;
            const bf16* vb = vbuf + ((size_t)b*CD + c)*HW;
            float acc = 0.f;
            #pragma unroll
            for (int t = 0; t < 9; ++t){
                int ir = r + t/3 - 1, icc = gcol + t%3 - 1;
                if ((unsigned)ir < 96u && (unsigned)icc < 96u)
                    acc += b2f(vb[ir*WD + icc]) * bs2f(w2s[px*152 + g9 + t]);
            }
            yt[c*52 + px] = acc;
        }
    }
    __syncthreads();
    {
        int c = tid & 127, half = tid >> 7;
        float s = 0.f, ss = 0.f;
        for (int px = half*24; px < half*24 + 24; ++px){
            float v = yt[c*52 + px]; s += v; ss += v*v;
        }
        blks[tid] = s; blkq[tid] = ss;
    }
    __syncthreads();
    if (tid < 128){
        float s = blks[tid] + blks[tid+128];
        float ss = blkq[tid] + blkq[tid+128];
        int slot = blk & 255;
        atomicAdd(&bnsum_s[tid*256 + slot], s);
        atomicAdd(&bnss_s [tid*256 + slot], ss);
    }
    for (int idx = tid; idx < 128*48; idx += 256){
        int c = idx / 48, px = idx - c*48;
        yout[((size_t)b*CD + c)*HW + r*WD + px0 + px] = yt[c*52 + px];
    }
}

// ---------------- GN finalize ----------------
__global__ void k_gnfin(const float* __restrict__ gsum_s, const float* __restrict__ gsq_s,
                        float* __restrict__ gmean, float* __restrict__ gistd){
    int i = threadIdx.x;
    float s = 0.f, ss = 0.f;
    for (int k = 0; k < 64; ++k){ s += gsum_s[i*64 + k]; ss += gsq_s[i*64 + k]; }
    float inv = 1.f / (9.f*HW);
    float m = s*inv;
    float var = ss*inv - m*m;
    gmean[i] = m;
    gistd[i] = rsqrtf(var + 1e-5f);
}

// ---------------- BN finalize ----------------
__global__ void k_bnfin(const float* __restrict__ bnsum_s, const float* __restrict__ bnss_s,
                        const float* __restrict__ canonf,
                        float* __restrict__ scale, float* __restrict__ shift){
    int c = threadIdx.x;
    float s = 0.f, ss = 0.f;
    for (int k = 0; k < 256; ++k){ s += bnsum_s[c*256 + k]; ss += bnss_s[c*256 + k]; }
    float inv = 1.f / (float)(BD*HW);
    float m = s*inv;
    float var = ss*inv - m*m;
    float sc = canonf[CO_BNG + c] * rsqrtf(var + 1e-5f);
    scale[c] = sc;
    shift[c] = canonf[CO_BNB + c] - m*sc;
}

// ---------------- GAP (read-only, float4, one block per (b,c), direct store) ----------------
__global__ void k_gap(const float* __restrict__ ybuf, const bf16* __restrict__ kbuf,
                      const float* __restrict__ scale, const float* __restrict__ shift,
                      float* __restrict__ gap){
    int bc = blockIdx.x;             // 1024 = b*CD + c
    int c = bc % CD;
    int tid = threadIdx.x;
    float sc = scale[c], sh = shift[c];
    const float4* y4 = (const float4*)ybuf + (size_t)bc*2304;
    const ushort4* k4 = (const ushort4*)kbuf + (size_t)bc*2304;
    float gs = 0.f;
    for (int k = 0; k < 9; ++k){
        int i = k*256 + tid;
        float4 yv = y4[i];
        ushort4 kv = k4[i];
        #pragma unroll
        for (int j = 0; j < 4; ++j){
            float yn = ((&yv.x)[j])*sc + sh;
            float ys = yn / (1.f + __expf(-yn));
            gs += ys + bs2f((short)((&kv.x)[j]));
        }
    }
    __shared__ float shm[256];
    shm[tid] = gs; __syncthreads();
    for (int st = 128; st > 0; st >>= 1){
        if (tid < st) shm[tid] += shm[tid+st];
        __syncthreads();
    }
    if (tid == 0) gap[bc] = shm[0];
}

// ---------------- SE ----------------
__global__ void k_se(const float* __restrict__ gap, const float* __restrict__ canonf,
                     float* __restrict__ p0, float* __restrict__ p1){
    int b = blockIdx.x;
    int tid = threadIdx.x;
    __shared__ float loc[128], h1[64];
    float invhw = 1.f / (float)HW;
    loc[tid]      = gap[b*CD + tid]      * invhw;
    loc[tid + 64] = gap[b*CD + tid + 64] * invhw;
    __syncthreads();
    {
        const float* wr = canonf + CO_SW1 + (size_t)tid*128;
        float acc = canonf[CO_SB1 + tid];
        for (int c = 0; c < 128; ++c) acc += wr[c] * loc[c];
        h1[tid] = fmaxf(acc, 0.f);
    }
    __syncthreads();
    for (int c = tid; c < 128; c += 64){
        float a0 = canonf[CO_SB2 + 2*c], a1 = canonf[CO_SB2 + 2*c+1];
        const float* w0 = canonf + CO_SW2 + (size_t)(2*c)*64;
        const float* w1p = canonf + CO_SW2 + (size_t)(2*c+1)*64;
        for (int j = 0; j < 64; ++j){
            a0 += w0[j] * h1[j];
            a1 += w1p[j] * h1[j];
        }
        float mx = fmaxf(a0, a1);
        float e0 = __expf(a0-mx), e1 = __expf(a1-mx);
        float inv = 1.f / (e0 + e1);
        p0[b*CD+c] = e0*inv;
        p1[b*CD+c] = e1*inv;
    }
}

// ---------------- out: float4 recompute BN+swish, blend, in-place ----------------
__global__ void k_out(float* __restrict__ ybuf, const bf16* __restrict__ kbuf,
                      const float* __restrict__ scale, const float* __restrict__ shift,
                      const float* __restrict__ p0, const float* __restrict__ p1){
    size_t idx = (size_t)blockIdx.x*256 + threadIdx.x;   // vec4 index, NTOT/4
    int bc = (int)(idx / 2304);
    int c = bc % CD;
    float sc = scale[c], sh = shift[c];
    float q0 = p0[bc], q1 = p1[bc];
    float4 yv = ((const float4*)ybuf)[idx];
    ushort4 kv = ((const ushort4*)kbuf)[idx];
    float4 ov;
    #pragma unroll
    for (int j = 0; j < 4; ++j){
        float yn = ((&yv.x)[j])*sc + sh;
        float ys = yn / (1.f + __expf(-yn));
        (&ov.x)[j] = ys*q0 + bs2f((short)((&kv.x)[j]))*q1;
    }
    ((float4*)ybuf)[idx] = ov;
}

extern "C" void kernel_launch(void* const* d_in, const int* in_sizes, int n_in,
                              void* d_out, int out_size, void* d_ws, size_t ws_size,
                              hipStream_t stream) {
    TensPtrs tp;
    for (int i = 0; i < 14; ++i) tp.p[i] = d_in[i];

    float* f = (float*)d_ws;
    float* bnsum_s = f;            // 32768 (zeroed)
    float* bnss_s  = f + 32768;    // 32768 (zeroed)
    float* gsum_s  = f + 65536;    // 8192  (zeroed)
    float* gsq_s   = f + 73728;    // 8192  (zeroed)
    float* gap     = f + 81920;    // 1024  (zeroed)
    float* gmean   = f + 82944;
    float* gistd   = f + 83072;
    float* bscale  = f + 83200;
    float* bshift  = f + 83328;
    float* p0      = f + 83456;
    float* p1      = f + 84480;
    int*   flags = (int*)((char*)d_ws + 393216);
    float* canonf = (float*)((char*)d_ws + 425984);
    short* canonb = (short*)((char*)d_ws + 860160);
    bf16*  kbuf  = (bf16*)((char*)d_ws + 1048576);        // 18.87 MB
    bf16*  vbuf  = kbuf + NTOT;                           // 18.87 MB (ends 38,797,312)
    unsigned short* w1b = (unsigned short*)((char*)d_ws + 38797312);  // 9.44 MB (ends 48,234,496)
    float* ybuf  = (float*)d_out;
    short* kwre = (short*)((char*)d_out + KWRE_OFF);      // d_out scratch (pre-y)
    unsigned short* xb16 = (unsigned short*)d_out;        // d_out scratch [0,18.9MB) (pre-y)

    bool fast = ws_size >= 48234496ull;

    k_detect<<<14, 64, 0, stream>>>(tp, flags);
    k_canon<<<13, 256, 0, stream>>>(tp, flags, canonf, canonb);
    k_xcast<<<(int)(NTOT/4/256), 256, 0, stream>>>(d_in[0], flags, xb16);
    k_reorder_kw<<<144, 256, 0, stream>>>(canonb, kwre);
    k_zero<<<324, 256, 0, stream>>>(f, 82944);
    k_keyconv_mfma<<<768, 256, 0, stream>>>((const short*)xb16, kwre, kbuf);
    if (fast){
        k_embed_stats<<<1536, 256, 0, stream>>>((const short*)xb16, kbuf, canonb, canonf,
                                                w1b, vbuf, gsum_s, gsq_s);
        k_gnfin<<<1, 128, 0, stream>>>(gsum_s, gsq_s, gmean, gistd);
        k_embed_apply<<<1536, 256, 0, stream>>>(w1b, canonb, canonf, gmean, gistd,
                                                vbuf, ybuf);
        k_bnstat<<<1024, 256, 0, stream>>>(ybuf, bnsum_s, bnss_s);
    } else {
        k_embed_mfma<false><<<1536, 256, 0, stream>>>(d_in[0], flags, kbuf, canonb, canonf,
                                                      gmean, gistd, vbuf, ybuf,
                                                      gsum_s, gsq_s, bnsum_s, bnss_s);
        k_gnfin<<<1, 128, 0, stream>>>(gsum_s, gsq_s, gmean, gistd);
        k_vconv_mfma<<<768, 256, 0, stream>>>(d_in[0], flags, canonb, vbuf);
        k_embed_mfma<true><<<1536, 256, 0, stream>>>(d_in[0], flags, kbuf, canonb, canonf,
                                                     gmean, gistd, vbuf, ybuf,
                                                     gsum_s, gsq_s, bnsum_s, bnss_s);
    }
    k_bnfin<<<1, 128, 0, stream>>>(bnsum_s, bnss_s, canonf, bscale, bshift);
    k_gap<<<1024, 256, 0, stream>>>(ybuf, kbuf, bscale, bshift, gap);
    k_se<<<BD, 64, 0, stream>>>(gap, canonf, p0, p1);
    k_out<<<(int)(NTOT/4/256), 256, 0, stream>>>(ybuf, kbuf, bscale, bshift, p0, p1);
}